// Round 1
// baseline (1907.540 us; speedup 1.0000x reference)
//
#include <hip/hip_runtime.h>
#include <hip/hip_bf16.h>
#include <math.h>

#define DIMC  256
#define HEADS 8
#define DH    64
#define INNER 512
#define TOPK  512
#define LQ    16384
#define LKE   4096
#define NB    2
#define NBH   16

// ---------------- channel-LN stats: one thread per (b,l) ----------------
__global__ void stats_kernel(const float* __restrict__ x, float* __restrict__ mu,
                             float* __restrict__ rs, int L, int total) {
    int idx = blockIdx.x * 256 + threadIdx.x;
    if (idx >= total) return;
    int b = idx / L, l = idx - b * L;
    const float* p = x + (size_t)b * DIMC * L + l;
    float s = 0.f, sq = 0.f;
    for (int c = 0; c < DIMC; c++) {
        float v = p[(size_t)c * L];
        s += v; sq += v * v;
    }
    float m = s * (1.0f / DIMC);
    float var = fmaxf(sq * (1.0f / DIMC) - m * m, 0.f);
    mu[idx] = m;
    rs[idx] = rsqrtf(var + 1e-5f);
}

// ---------------- projection GEMM with fused input-LN and per-head L2 norm ----
// C[o0+0..63][l0+0..63] = sum_c W[o][c] * LN(x)[c][l]; tile 64x64, Kchunk 32.
__global__ __launch_bounds__(256) void gemm_proj_kernel(
    const float* __restrict__ w, const float* __restrict__ x,
    const float* __restrict__ mu, const float* __restrict__ rs,
    const float* __restrict__ g, const float* __restrict__ beta,
    int L, int nKTiles, float* __restrict__ kdst, float* __restrict__ vdst) {
    int lt = blockIdx.x, ot = blockIdx.y, b = blockIdx.z;
    int l0 = lt * 64, o0 = ot * 64;
    __shared__ float Ws[64][33];
    __shared__ float Xs[32][65];
    __shared__ float Cs[64][65];
    __shared__ float nf[64];
    int t = threadIdx.x;
    int tx = t & 15, ty = t >> 4;
    float acc[4][4];
#pragma unroll
    for (int a = 0; a < 4; a++)
#pragma unroll
        for (int c2 = 0; c2 < 4; c2++) acc[a][c2] = 0.f;
    for (int kc = 0; kc < DIMC; kc += 32) {
#pragma unroll
        for (int r = 0; r < 8; r++) {
            int f = r * 256 + t;
            int oi = f >> 5, kj = f & 31;
            Ws[oi][kj] = w[(size_t)(o0 + oi) * DIMC + kc + kj];
        }
#pragma unroll
        for (int r = 0; r < 8; r++) {
            int f = r * 256 + t;
            int kj = f >> 6, lj = f & 63;
            int loc = b * L + l0 + lj;
            float v = x[(size_t)b * DIMC * L + (size_t)(kc + kj) * L + (l0 + lj)];
            Xs[kj][lj] = (v - mu[loc]) * rs[loc] * g[kc + kj] + beta[kc + kj];
        }
        __syncthreads();
#pragma unroll
        for (int kj = 0; kj < 32; kj++) {
            float wr[4], xr[4];
#pragma unroll
            for (int a = 0; a < 4; a++) wr[a] = Ws[ty * 4 + a][kj];
#pragma unroll
            for (int c2 = 0; c2 < 4; c2++) xr[c2] = Xs[kj][tx * 4 + c2];
#pragma unroll
            for (int a = 0; a < 4; a++)
#pragma unroll
                for (int c2 = 0; c2 < 4; c2++) acc[a][c2] += wr[a] * xr[c2];
        }
        __syncthreads();
    }
#pragma unroll
    for (int a = 0; a < 4; a++)
#pragma unroll
        for (int c2 = 0; c2 < 4; c2++) Cs[ty * 4 + a][tx * 4 + c2] = acc[a][c2];
    __syncthreads();
    bool is_k = (ot < nKTiles);
    if (t < 64) {
        if (is_k) {
            float sq = 0.f;
            for (int o = 0; o < 64; o++) { float v = Cs[o][t]; sq += v * v; }
            nf[t] = 1.0f / fmaxf(sqrtf(sq), 1e-12f);
        } else {
            nf[t] = 1.0f;
        }
    }
    __syncthreads();
    int h = is_k ? ot : (ot - nKTiles);
    float* dst = is_k ? kdst : vdst;
    size_t base = ((size_t)(b * HEADS + h) * L + l0) * 64;
#pragma unroll
    for (int r = 0; r < 16; r++) {
        int f = r * 256 + t;
        int d = f & 63, lj = f >> 6;
        dst[base + (size_t)lj * 64 + d] = Cs[d][lj] * nf[lj];
    }
}

// ---------------- gather sampled queries ----------------
__global__ void gather_q_kernel(const float* __restrict__ qf, const int* __restrict__ ridx,
                                float* __restrict__ Qsm) {
    int idx = blockIdx.x * 256 + threadIdx.x;   // NBH*TOPK*64
    int d = idx & 63;
    int ti = (idx >> 6) & (TOPK - 1);
    int bh = idx >> 15;
    int row = ridx[bh * TOPK + ti];
    Qsm[idx] = qf[((size_t)bh * LQ + row) * 64 + d];
}

// ---------------- L1 cdist + min over sampled queries ----------------
__global__ __launch_bounds__(256) void cdist_min_kernel(
    const float* __restrict__ kf, const float* __restrict__ Qsm,
    float* __restrict__ min_d) {
    int bh = blockIdx.y, kt = blockIdx.x;
    int t = threadIdx.x;
    int i = t & 63, jg = t >> 6;
    __shared__ float Ks[64][65];
    __shared__ float Qc[64][68];   // [d][j]
    __shared__ float part[4][64];
    const float* kbase = kf + ((size_t)bh * LKE + (size_t)kt * 64) * 64;
#pragma unroll
    for (int rr = 0; rr < 16; rr++) {
        int f = rr * 256 + t;
        int row = f >> 6, d = f & 63;
        Ks[row][d] = kbase[(size_t)row * 64 + d];
    }
    float best = 3.0e38f;
    const float* qb = Qsm + (size_t)bh * TOPK * 64;
    for (int qc = 0; qc < TOPK; qc += 64) {
        __syncthreads();
#pragma unroll
        for (int rr = 0; rr < 16; rr++) {
            int f = rr * 256 + t;
            int j = f >> 6, d = f & 63;
            Qc[d][j] = qb[(size_t)(qc + j) * 64 + d];
        }
        __syncthreads();
        float acc[16];
#pragma unroll
        for (int jj = 0; jj < 16; jj++) acc[jj] = 0.f;
#pragma unroll 4
        for (int d = 0; d < 64; d++) {
            float kd = Ks[i][d];
            const float4* qr = (const float4*)&Qc[d][jg * 16];
            float4 a0 = qr[0], a1 = qr[1], a2 = qr[2], a3 = qr[3];
            acc[0]  += fabsf(kd - a0.x); acc[1]  += fabsf(kd - a0.y);
            acc[2]  += fabsf(kd - a0.z); acc[3]  += fabsf(kd - a0.w);
            acc[4]  += fabsf(kd - a1.x); acc[5]  += fabsf(kd - a1.y);
            acc[6]  += fabsf(kd - a1.z); acc[7]  += fabsf(kd - a1.w);
            acc[8]  += fabsf(kd - a2.x); acc[9]  += fabsf(kd - a2.y);
            acc[10] += fabsf(kd - a2.z); acc[11] += fabsf(kd - a2.w);
            acc[12] += fabsf(kd - a3.x); acc[13] += fabsf(kd - a3.y);
            acc[14] += fabsf(kd - a3.z); acc[15] += fabsf(kd - a3.w);
        }
#pragma unroll
        for (int jj = 0; jj < 16; jj++) best = fminf(best, acc[jj]);
    }
    part[jg][i] = best;
    __syncthreads();
    if (t < 64) {
        float v = fminf(fminf(part[0][t], part[1][t]), fminf(part[2][t], part[3][t]));
        min_d[(size_t)bh * LKE + (size_t)kt * 64 + t] = v;
    }
}

// ---------------- radix-select 512 smallest per row (deterministic) ----------
__global__ void select_topk_kernel(const float* __restrict__ min_d, int* __restrict__ isel) {
    int bh = blockIdx.x;
    int t = threadIdx.x;  // 256
    __shared__ unsigned su[LKE];
    __shared__ int hist[256];
    __shared__ int sb[2];
    for (int i = t; i < LKE; i += 256)
        su[i] = __float_as_uint(min_d[(size_t)bh * LKE + i]);  // nonneg floats: monotone bits
    unsigned prefix = 0, mask = 0;
    int need = TOPK;
    for (int shift = 24; shift >= 0; shift -= 8) {
        hist[t] = 0;
        __syncthreads();
        for (int i = t; i < LKE; i += 256) {
            unsigned u = su[i];
            if ((u & mask) == prefix) atomicAdd(&hist[(u >> shift) & 255], 1);
        }
        __syncthreads();
        if (t == 0) {
            int c = 0, bsel = 0;
            for (; bsel < 255; bsel++) {
                if (c + hist[bsel] >= need) break;
                c += hist[bsel];
            }
            sb[0] = bsel; sb[1] = need - c;
        }
        __syncthreads();
        prefix |= ((unsigned)sb[0]) << shift;
        mask |= (255u << shift);
        need = sb[1];
        __syncthreads();
    }
    // ordered collection by wave 0: all < prefix, then first `need` == prefix by index
    if (t < 64) {
        int pos = 0, eqseen = 0;
        unsigned long long lanem1 = (t == 0) ? 0ull : ((1ull << t) - 1ull);
        for (int i0 = 0; i0 < LKE; i0 += 64) {
            unsigned u = su[i0 + t];
            bool lt = (u < prefix);
            bool eq = (u == prefix);
            unsigned long long be = __ballot(eq);
            int eqbefore = __popcll(be & lanem1);
            bool take = lt || (eq && (eqseen + eqbefore) < need);
            unsigned long long bt = __ballot(take);
            if (take) isel[bh * TOPK + pos + __popcll(bt & lanem1)] = i0 + t;
            pos += __popcll(bt);
            eqseen += __popcll(be);
        }
    }
}

// ---------------- gather selected K/V ----------------
__global__ void gather_kv_kernel(const float* __restrict__ kf, const float* __restrict__ vf,
                                 const int* __restrict__ isel,
                                 float* __restrict__ ksel, float* __restrict__ vsel) {
    int idx = blockIdx.x * 256 + threadIdx.x;
    int d = idx & 63;
    int ti = (idx >> 6) & (TOPK - 1);
    int bh = idx >> 15;
    int row = isel[bh * TOPK + ti];
    size_t src = ((size_t)bh * LKE + row) * 64 + d;
    ksel[idx] = kf[src];
    vsel[idx] = vf[src];
}

// ---------------- flash-style attention over 512 selected keys ----------------
// block: 256 thr = 4 waves, 64 q-rows; lane(r=lane&15, dc=lane>>4); keys j=dc+4*jj.
__global__ __launch_bounds__(256) void attn_kernel(
    const float* __restrict__ qf, const float* __restrict__ ksel,
    const float* __restrict__ vsel, float* __restrict__ af) {
    int bh = blockIdx.y, rt = blockIdx.x;
    int t = threadIdx.x;
    int w = t >> 6, lane = t & 63;
    int r = lane & 15, dc = lane >> 4;
    int qrow = w * 16 + r;   // 0..63
    __shared__ float Qs[64][68];
    __shared__ float KP[64][68];   // K chunk, then per-wave P rows
    __shared__ float Vs[64][68];
    const float* qbase = qf + ((size_t)bh * LQ + (size_t)rt * 64) * 64;
#pragma unroll
    for (int rr = 0; rr < 16; rr++) {
        int f = rr * 256 + t;
        int row = f >> 6, d = f & 63;
        Qs[row][d] = qbase[(size_t)row * 64 + d];
    }
    float m = -3.0e38f, lsum = 0.f;
    float oacc[16];
#pragma unroll
    for (int i = 0; i < 16; i++) oacc[i] = 0.f;
    const float* kb = ksel + (size_t)bh * TOPK * 64;
    const float* vb = vsel + (size_t)bh * TOPK * 64;

    for (int kc = 0; kc < TOPK; kc += 64) {
        __syncthreads();   // previous PV done (and first Q staging)
#pragma unroll
        for (int rr = 0; rr < 16; rr++) {
            int f = rr * 256 + t;
            int row = f >> 6, d = f & 63;
            KP[row][d] = kb[(size_t)(kc + row) * 64 + d];
            Vs[row][d] = vb[(size_t)(kc + row) * 64 + d];
        }
        __syncthreads();
        // scores for 16 keys (strided by 4 to avoid LDS bank aliasing)
        float s[16];
#pragma unroll
        for (int jj = 0; jj < 16; jj++) s[jj] = 0.f;
#pragma unroll
        for (int d4 = 0; d4 < 16; d4++) {
            float4 q4 = *(const float4*)&Qs[qrow][d4 * 4];
#pragma unroll
            for (int jj = 0; jj < 16; jj++) {
                float4 k4 = *(const float4*)&KP[dc + 4 * jj][d4 * 4];
                s[jj] += q4.x * k4.x + q4.y * k4.y + q4.z * k4.z + q4.w * k4.w;
            }
        }
        // online softmax update
        float cmax = s[0];
#pragma unroll
        for (int jj = 1; jj < 16; jj++) cmax = fmaxf(cmax, s[jj]);
        cmax = fmaxf(cmax, __shfl_xor(cmax, 16));
        cmax = fmaxf(cmax, __shfl_xor(cmax, 32));
        float newm = fmaxf(m, cmax);
        float scale = __expf(m - newm);
        float p[16];
        float csum = 0.f;
#pragma unroll
        for (int jj = 0; jj < 16; jj++) { p[jj] = __expf(s[jj] - newm); csum += p[jj]; }
        csum += __shfl_xor(csum, 16);
        csum += __shfl_xor(csum, 32);
        lsum = lsum * scale + csum;
        m = newm;
#pragma unroll
        for (int i = 0; i < 16; i++) oacc[i] *= scale;
        __syncthreads();   // all waves done reading K
#pragma unroll
        for (int jj = 0; jj < 16; jj++) KP[qrow][dc + 4 * jj] = p[jj];
        __syncthreads();   // P visible
        // PV: oacc[i] for d = dc*16 + i
#pragma unroll 8
        for (int j = 0; j < 64; j++) {
            float pj = KP[qrow][j];
            const float4* vr = (const float4*)&Vs[j][dc * 16];
            float4 v0 = vr[0], v1 = vr[1], v2 = vr[2], v3 = vr[3];
            oacc[0]  += pj * v0.x; oacc[1]  += pj * v0.y; oacc[2]  += pj * v0.z; oacc[3]  += pj * v0.w;
            oacc[4]  += pj * v1.x; oacc[5]  += pj * v1.y; oacc[6]  += pj * v1.z; oacc[7]  += pj * v1.w;
            oacc[8]  += pj * v2.x; oacc[9]  += pj * v2.y; oacc[10] += pj * v2.z; oacc[11] += pj * v2.w;
            oacc[12] += pj * v3.x; oacc[13] += pj * v3.y; oacc[14] += pj * v3.z; oacc[15] += pj * v3.w;
        }
    }
    float inv = 1.0f / lsum;
    float4* ob4 = (float4*)(af + ((size_t)bh * LQ + (size_t)rt * 64 + qrow) * 64 + dc * 16);
    ob4[0] = make_float4(oacc[0] * inv, oacc[1] * inv, oacc[2] * inv, oacc[3] * inv);
    ob4[1] = make_float4(oacc[4] * inv, oacc[5] * inv, oacc[6] * inv, oacc[7] * inv);
    ob4[2] = make_float4(oacc[8] * inv, oacc[9] * inv, oacc[10] * inv, oacc[11] * inv);
    ob4[3] = make_float4(oacc[12] * inv, oacc[13] * inv, oacc[14] * inv, oacc[15] * inv);
}

// ---------------- output projection GEMM (fold af -> channels) ----------------
__global__ __launch_bounds__(256) void gemm_out_kernel(
    const float* __restrict__ w, const float* __restrict__ af, float* __restrict__ pre) {
    int lt = blockIdx.x, ot = blockIdx.y, b = blockIdx.z;
    int l0 = lt * 64, o0 = ot * 64;
    __shared__ float Ws[64][33];
    __shared__ float Xs[32][65];
    __shared__ float Cs[64][65];
    int t = threadIdx.x, tx = t & 15, ty = t >> 4;
    float acc[4][4];
#pragma unroll
    for (int a = 0; a < 4; a++)
#pragma unroll
        for (int c2 = 0; c2 < 4; c2++) acc[a][c2] = 0.f;
    for (int kc = 0; kc < INNER; kc += 32) {
        int h = kc >> 6;
        int d0 = kc & 63;
#pragma unroll
        for (int r = 0; r < 8; r++) {
            int f = r * 256 + t;
            int oi = f >> 5, cj = f & 31;
            Ws[oi][cj] = w[(size_t)(o0 + oi) * INNER + kc + cj];
        }
#pragma unroll
        for (int r = 0; r < 8; r++) {
            int f = r * 256 + t;
            int lj = f >> 5, cj = f & 31;
            Xs[cj][lj] = af[((size_t)(b * HEADS + h) * LQ + l0 + lj) * 64 + d0 + cj];
        }
        __syncthreads();
#pragma unroll
        for (int kj = 0; kj < 32; kj++) {
            float wr[4], xr[4];
#pragma unroll
            for (int a = 0; a < 4; a++) wr[a] = Ws[ty * 4 + a][kj];
#pragma unroll
            for (int c2 = 0; c2 < 4; c2++) xr[c2] = Xs[kj][tx * 4 + c2];
#pragma unroll
            for (int a = 0; a < 4; a++)
#pragma unroll
                for (int c2 = 0; c2 < 4; c2++) acc[a][c2] += wr[a] * xr[c2];
        }
        __syncthreads();
    }
#pragma unroll
    for (int a = 0; a < 4; a++)
#pragma unroll
        for (int c2 = 0; c2 < 4; c2++) Cs[ty * 4 + a][tx * 4 + c2] = acc[a][c2];
    __syncthreads();
#pragma unroll
    for (int r = 0; r < 16; r++) {
        int f = r * 256 + t;
        int lj = f & 63, oi = f >> 6;
        pre[((size_t)(b * DIMC + o0 + oi)) * LQ + l0 + lj] = Cs[oi][lj];
    }
}

// ---------------- final LN + gamma*x + residual ----------------
__global__ void final_kernel(const float* __restrict__ pre, const float* __restrict__ mu,
                             const float* __restrict__ rs, const float* __restrict__ g,
                             const float* __restrict__ beta, const float* __restrict__ gamma,
                             const float* __restrict__ qs_in, float* __restrict__ out) {
    size_t idx = (size_t)blockIdx.x * 256 + threadIdx.x;
    int l = (int)(idx & (LQ - 1));
    int o = (int)((idx >> 14) & 255);
    int b = (int)(idx >> 22);
    int loc = b * LQ + l;
    float xn = (pre[idx] - mu[loc]) * rs[loc] * g[o] + beta[o];
    out[idx] = gamma[0] * xn + qs_in[idx];
}

extern "C" void kernel_launch(void* const* d_in, const int* in_sizes, int n_in,
                              void* d_out, int out_size, void* d_ws, size_t ws_size,
                              hipStream_t stream) {
    const float* qs_in = (const float*)d_in[0];
    const float* ctx   = (const float*)d_in[1];
    const int*   ridx  = (const int*)d_in[2];
    const float* g_ctx = (const float*)d_in[3];
    const float* b_ctx = (const float*)d_in[4];
    const float* g_qs  = (const float*)d_in[5];
    const float* b_qs  = (const float*)d_in[6];
    const float* w_kv  = (const float*)d_in[7];
    const float* w_q   = (const float*)d_in[8];
    const float* w_out = (const float*)d_in[9];
    const float* g_out = (const float*)d_in[10];
    const float* b_out = (const float*)d_in[11];
    const float* gamma = (const float*)d_in[12];
    float* out = (float*)d_out;

    float* ws = (float*)d_ws;
    size_t off = 0;
    float* kf    = ws + off; off += (size_t)NBH * LKE * 64;   // 4.19M
    float* vf    = ws + off; off += (size_t)NBH * LKE * 64;   // 4.19M
    float* qf    = ws + off; off += (size_t)NBH * LQ * 64;    // 16.8M
    float* af    = ws + off; off += (size_t)NBH * LQ * 64;    // 16.8M
    float* Qsm   = ws + off; off += (size_t)NBH * TOPK * 64;
    float* kselp = ws + off; off += (size_t)NBH * TOPK * 64;
    float* vselp = ws + off; off += (size_t)NBH * TOPK * 64;
    float* pre   = ws + off; off += (size_t)NB * DIMC * LQ;   // 8.39M
    float* min_d = ws + off; off += (size_t)NBH * LKE;
    float* mu_c  = ws + off; off += NB * LKE;
    float* rs_c  = ws + off; off += NB * LKE;
    float* mu_q  = ws + off; off += NB * LQ;
    float* rs_q  = ws + off; off += NB * LQ;
    float* mu_o  = ws + off; off += NB * LQ;
    float* rs_o  = ws + off; off += NB * LQ;
    int*   isel  = (int*)(ws + off); off += NBH * TOPK;

    stats_kernel<<<(NB * LKE + 255) / 256, 256, 0, stream>>>(ctx, mu_c, rs_c, LKE, NB * LKE);
    stats_kernel<<<(NB * LQ + 255) / 256, 256, 0, stream>>>(qs_in, mu_q, rs_q, LQ, NB * LQ);
    gemm_proj_kernel<<<dim3(LKE / 64, 16, NB), 256, 0, stream>>>(
        w_kv, ctx, mu_c, rs_c, g_ctx, b_ctx, LKE, 8, kf, vf);
    gemm_proj_kernel<<<dim3(LQ / 64, 8, NB), 256, 0, stream>>>(
        w_q, qs_in, mu_q, rs_q, g_qs, b_qs, LQ, 8, qf, qf);
    gather_q_kernel<<<(NBH * TOPK * 64) / 256, 256, 0, stream>>>(qf, ridx, Qsm);
    cdist_min_kernel<<<dim3(LKE / 64, NBH), 256, 0, stream>>>(kf, Qsm, min_d);
    select_topk_kernel<<<NBH, 256, 0, stream>>>(min_d, isel);
    gather_kv_kernel<<<(NBH * TOPK * 64) / 256, 256, 0, stream>>>(kf, vf, isel, kselp, vselp);
    attn_kernel<<<dim3(LQ / 64, NBH), 256, 0, stream>>>(qf, kselp, vselp, af);
    gemm_out_kernel<<<dim3(LQ / 64, DIMC / 64, NB), 256, 0, stream>>>(w_out, af, pre);
    stats_kernel<<<(NB * LQ + 255) / 256, 256, 0, stream>>>(pre, mu_o, rs_o, LQ, NB * LQ);
    final_kernel<<<(NB * DIMC * LQ) / 256, 256, 0, stream>>>(
        pre, mu_o, rs_o, g_out, b_out, gamma, qs_in, out);
}

// Round 3
// 862.938 us; speedup vs baseline: 2.2105x; 2.2105x over previous
//
#include <hip/hip_runtime.h>
#include <hip/hip_bf16.h>
#include <math.h>

#define DIMC  256
#define HEADS 8
#define DH    64
#define INNER 512
#define TOPK  512
#define LQ    16384
#define LKE   4096
#define NB    2
#define NBH   16

typedef __attribute__((ext_vector_type(8))) short bf16x8;
typedef __attribute__((ext_vector_type(4))) float f32x4;

__device__ __forceinline__ unsigned short f2bf(float f) {
    unsigned u = __float_as_uint(f);
    u += 0x7FFFu + ((u >> 16) & 1u);
    return (unsigned short)(u >> 16);
}
__device__ __forceinline__ float bf2f(unsigned short b) {
    return __uint_as_float(((unsigned)b) << 16);
}
__device__ __forceinline__ f32x4 mfma16(bf16x8 a, bf16x8 b, f32x4 c) {
    return __builtin_amdgcn_mfma_f32_16x16x32_bf16(a, b, c, 0, 0, 0);
}

// ---------------- channel-LN stats: one thread per (b,l) ----------------
__global__ void stats_kernel(const float* __restrict__ x, float* __restrict__ mu,
                             float* __restrict__ rs, int L, int total) {
    int idx = blockIdx.x * 256 + threadIdx.x;
    if (idx >= total) return;
    int b = idx / L, l = idx - b * L;
    const float* p = x + (size_t)b * DIMC * L + l;
    float s = 0.f, sq = 0.f;
    for (int c = 0; c < DIMC; c++) {
        float v = p[(size_t)c * L];
        s += v; sq += v * v;
    }
    float m = s * (1.0f / DIMC);
    float var = fmaxf(sq * (1.0f / DIMC) - m * m, 0.f);
    mu[idx] = m;
    rs[idx] = rsqrtf(var + 1e-5f);
}

// ---------------- projection GEMM with fused input-LN and per-head L2 norm ----
template<bool BF16OUT>
__global__ __launch_bounds__(256) void gemm_proj_kernel(
    const float* __restrict__ w, const float* __restrict__ x,
    const float* __restrict__ mu, const float* __restrict__ rs,
    const float* __restrict__ g, const float* __restrict__ beta,
    int L, int nKTiles, void* __restrict__ kdst, void* __restrict__ vdst) {
    int lt = blockIdx.x, ot = blockIdx.y, b = blockIdx.z;
    int l0 = lt * 64, o0 = ot * 64;
    __shared__ float Ws[64][33];
    __shared__ float Xs[32][65];
    __shared__ float Cs[64][65];
    __shared__ float nf[64];
    int t = threadIdx.x;
    int tx = t & 15, ty = t >> 4;
    float acc[4][4];
#pragma unroll
    for (int a = 0; a < 4; a++)
#pragma unroll
        for (int c2 = 0; c2 < 4; c2++) acc[a][c2] = 0.f;
    for (int kc = 0; kc < DIMC; kc += 32) {
#pragma unroll
        for (int r = 0; r < 8; r++) {
            int f = r * 256 + t;
            int oi = f >> 5, kj = f & 31;
            Ws[oi][kj] = w[(size_t)(o0 + oi) * DIMC + kc + kj];
        }
#pragma unroll
        for (int r = 0; r < 8; r++) {
            int f = r * 256 + t;
            int kj = f >> 6, lj = f & 63;
            int loc = b * L + l0 + lj;
            float v = x[(size_t)b * DIMC * L + (size_t)(kc + kj) * L + (l0 + lj)];
            Xs[kj][lj] = (v - mu[loc]) * rs[loc] * g[kc + kj] + beta[kc + kj];
        }
        __syncthreads();
#pragma unroll
        for (int kj = 0; kj < 32; kj++) {
            float wr[4], xr[4];
#pragma unroll
            for (int a = 0; a < 4; a++) wr[a] = Ws[ty * 4 + a][kj];
#pragma unroll
            for (int c2 = 0; c2 < 4; c2++) xr[c2] = Xs[kj][tx * 4 + c2];
#pragma unroll
            for (int a = 0; a < 4; a++)
#pragma unroll
                for (int c2 = 0; c2 < 4; c2++) acc[a][c2] += wr[a] * xr[c2];
        }
        __syncthreads();
    }
#pragma unroll
    for (int a = 0; a < 4; a++)
#pragma unroll
        for (int c2 = 0; c2 < 4; c2++) Cs[ty * 4 + a][tx * 4 + c2] = acc[a][c2];
    __syncthreads();
    bool is_k = (ot < nKTiles);
    if (t < 64) {
        if (is_k) {
            float sq = 0.f;
            for (int o = 0; o < 64; o++) { float v = Cs[o][t]; sq += v * v; }
            nf[t] = 1.0f / fmaxf(sqrtf(sq), 1e-12f);
        } else {
            nf[t] = 1.0f;
        }
    }
    __syncthreads();
    int h = is_k ? ot : (ot - nKTiles);
    size_t base = ((size_t)(b * HEADS + h) * L + l0) * 64;
#pragma unroll
    for (int r = 0; r < 16; r++) {
        int f = r * 256 + t;
        int d = f & 63, lj = f >> 6;
        float v = Cs[d][lj] * nf[lj];
        if (BF16OUT) {
            unsigned short* dst = (unsigned short*)(is_k ? kdst : vdst);
            dst[base + (size_t)lj * 64 + d] = f2bf(v);
        } else {
            float* dst = (float*)(is_k ? kdst : vdst);
            dst[base + (size_t)lj * 64 + d] = v;
        }
    }
}

// ------- exact f32 sampled-query recompute: LN -> w_q proj -> l2norm ---------
__global__ __launch_bounds__(256) void qsample_kernel(
    const float* __restrict__ x, const float* __restrict__ mu, const float* __restrict__ rs,
    const float* __restrict__ g, const float* __restrict__ beta,
    const float* __restrict__ w, const int* __restrict__ ridx,
    float* __restrict__ Qsm) {
    int lt = blockIdx.x, bh = blockIdx.y;
    int b = bh >> 3, h = bh & 7;
    int t = threadIdx.x, tx = t & 15, ty = t >> 4;
    __shared__ float Ws[64][33];
    __shared__ float Xs[32][65];
    __shared__ float Cs[64][65];
    __shared__ float nf[64];
    __shared__ int lidx[64];
    if (t < 64) lidx[t] = ridx[bh * TOPK + lt * 64 + t];
    __syncthreads();
    float acc[4][4];
#pragma unroll
    for (int a = 0; a < 4; a++)
#pragma unroll
        for (int c2 = 0; c2 < 4; c2++) acc[a][c2] = 0.f;
    for (int kc = 0; kc < DIMC; kc += 32) {
#pragma unroll
        for (int r = 0; r < 8; r++) {
            int f = r * 256 + t;
            int oi = f >> 5, kj = f & 31;
            Ws[oi][kj] = w[(size_t)(h * 64 + oi) * DIMC + kc + kj];
        }
#pragma unroll
        for (int r = 0; r < 8; r++) {
            int f = r * 256 + t;
            int kj = f >> 6, lj = f & 63;
            int l = lidx[lj];
            int loc = b * LQ + l;
            float v = x[(size_t)b * DIMC * LQ + (size_t)(kc + kj) * LQ + l];
            Xs[kj][lj] = (v - mu[loc]) * rs[loc] * g[kc + kj] + beta[kc + kj];
        }
        __syncthreads();
#pragma unroll
        for (int kj = 0; kj < 32; kj++) {
            float wr[4], xr[4];
#pragma unroll
            for (int a = 0; a < 4; a++) wr[a] = Ws[ty * 4 + a][kj];
#pragma unroll
            for (int c2 = 0; c2 < 4; c2++) xr[c2] = Xs[kj][tx * 4 + c2];
#pragma unroll
            for (int a = 0; a < 4; a++)
#pragma unroll
                for (int c2 = 0; c2 < 4; c2++) acc[a][c2] += wr[a] * xr[c2];
        }
        __syncthreads();
    }
#pragma unroll
    for (int a = 0; a < 4; a++)
#pragma unroll
        for (int c2 = 0; c2 < 4; c2++) Cs[ty * 4 + a][tx * 4 + c2] = acc[a][c2];
    __syncthreads();
    if (t < 64) {
        float sq = 0.f;
        for (int o = 0; o < 64; o++) { float v = Cs[o][t]; sq += v * v; }
        nf[t] = 1.0f / fmaxf(sqrtf(sq), 1e-12f);
    }
    __syncthreads();
#pragma unroll
    for (int r = 0; r < 16; r++) {
        int f = r * 256 + t;
        int d = f & 63, lj = f >> 6;
        Qsm[((size_t)bh * TOPK + (size_t)lt * 64 + lj) * 64 + d] = Cs[d][lj] * nf[lj];
    }
}

// ---------------- L1 cdist + min over sampled queries ----------------
__global__ __launch_bounds__(256) void cdist_min_kernel(
    const float* __restrict__ kf, const float* __restrict__ Qsm,
    float* __restrict__ min_d) {
    int bh = blockIdx.y, kt = blockIdx.x;
    int t = threadIdx.x;
    int i = t & 63, jg = t >> 6;
    __shared__ float Ks[64][65];
    __shared__ float Qc[64][68];   // [d][j]
    __shared__ float part[4][64];
    const float* kbase = kf + ((size_t)bh * LKE + (size_t)kt * 64) * 64;
#pragma unroll
    for (int rr = 0; rr < 16; rr++) {
        int f = rr * 256 + t;
        int row = f >> 6, d = f & 63;
        Ks[row][d] = kbase[(size_t)row * 64 + d];
    }
    float best = 3.0e38f;
    const float* qb = Qsm + (size_t)bh * TOPK * 64;
    for (int qc = 0; qc < TOPK; qc += 64) {
        __syncthreads();
#pragma unroll
        for (int rr = 0; rr < 16; rr++) {
            int f = rr * 256 + t;
            int j = f >> 6, d = f & 63;
            Qc[d][j] = qb[(size_t)(qc + j) * 64 + d];
        }
        __syncthreads();
        float acc[16];
#pragma unroll
        for (int jj = 0; jj < 16; jj++) acc[jj] = 0.f;
#pragma unroll 4
        for (int d = 0; d < 64; d++) {
            float kd = Ks[i][d];
            const float4* qr = (const float4*)&Qc[d][jg * 16];
            float4 a0 = qr[0], a1 = qr[1], a2 = qr[2], a3 = qr[3];
            acc[0]  += fabsf(kd - a0.x); acc[1]  += fabsf(kd - a0.y);
            acc[2]  += fabsf(kd - a0.z); acc[3]  += fabsf(kd - a0.w);
            acc[4]  += fabsf(kd - a1.x); acc[5]  += fabsf(kd - a1.y);
            acc[6]  += fabsf(kd - a1.z); acc[7]  += fabsf(kd - a1.w);
            acc[8]  += fabsf(kd - a2.x); acc[9]  += fabsf(kd - a2.y);
            acc[10] += fabsf(kd - a2.z); acc[11] += fabsf(kd - a2.w);
            acc[12] += fabsf(kd - a3.x); acc[13] += fabsf(kd - a3.y);
            acc[14] += fabsf(kd - a3.z); acc[15] += fabsf(kd - a3.w);
        }
#pragma unroll
        for (int jj = 0; jj < 16; jj++) best = fminf(best, acc[jj]);
    }
    part[jg][i] = best;
    __syncthreads();
    if (t < 64) {
        float v = fminf(fminf(part[0][t], part[1][t]), fminf(part[2][t], part[3][t]));
        min_d[(size_t)bh * LKE + (size_t)kt * 64 + t] = v;
    }
}

// ---------------- radix-select 512 smallest per row (deterministic) ----------
__global__ void select_topk_kernel(const float* __restrict__ min_d, int* __restrict__ isel) {
    int bh = blockIdx.x;
    int t = threadIdx.x;  // 256
    __shared__ unsigned su[LKE];
    __shared__ int hist[256];
    __shared__ int sb[2];
    for (int i = t; i < LKE; i += 256)
        su[i] = __float_as_uint(min_d[(size_t)bh * LKE + i]);
    unsigned prefix = 0, mask = 0;
    int need = TOPK;
    for (int shift = 24; shift >= 0; shift -= 8) {
        hist[t] = 0;
        __syncthreads();
        for (int i = t; i < LKE; i += 256) {
            unsigned u = su[i];
            if ((u & mask) == prefix) atomicAdd(&hist[(u >> shift) & 255], 1);
        }
        __syncthreads();
        if (t == 0) {
            int c = 0, bsel = 0;
            for (; bsel < 255; bsel++) {
                if (c + hist[bsel] >= need) break;
                c += hist[bsel];
            }
            sb[0] = bsel; sb[1] = need - c;
        }
        __syncthreads();
        prefix |= ((unsigned)sb[0]) << shift;
        mask |= (255u << shift);
        need = sb[1];
        __syncthreads();
    }
    if (t < 64) {
        int pos = 0, eqseen = 0;
        unsigned long long lanem1 = (t == 0) ? 0ull : ((1ull << t) - 1ull);
        for (int i0 = 0; i0 < LKE; i0 += 64) {
            unsigned u = su[i0 + t];
            bool lt = (u < prefix);
            bool eq = (u == prefix);
            unsigned long long be = __ballot(eq);
            int eqbefore = __popcll(be & lanem1);
            bool take = lt || (eq && (eqseen + eqbefore) < need);
            unsigned long long bt = __ballot(take);
            if (take) isel[bh * TOPK + pos + __popcll(bt & lanem1)] = i0 + t;
            pos += __popcll(bt);
            eqseen += __popcll(be);
        }
    }
}

// ---------------- gather selected K (f32 -> bf16, [bh][key][d]) ----------------
__global__ void gather_k_kernel(const float* __restrict__ kf, const int* __restrict__ isel,
                                unsigned short* __restrict__ kselh) {
    int idx = blockIdx.x * 256 + threadIdx.x;
    int d = idx & 63;
    int ti = (idx >> 6) & (TOPK - 1);
    int bh = idx >> 15;
    int row = isel[bh * TOPK + ti];
    kselh[idx] = f2bf(kf[((size_t)bh * LKE + row) * 64 + d]);
}

// ---------------- gather selected V transposed (f32, [bh][d][key]) ------
__global__ __launch_bounds__(256) void gather_vT_kernel(
    const float* __restrict__ vf, const int* __restrict__ isel,
    float* __restrict__ vTf) {
    int bh = blockIdx.y, kc = blockIdx.x * 64;
    int t = threadIdx.x;
    __shared__ float T[64][65];
#pragma unroll
    for (int r = 0; r < 4; r++) {
        int c = r * 256 + t;          // 1024 float4 chunks
        int row = c >> 4, c4 = c & 15;
        int krow = isel[bh * TOPK + kc + row];
        float4 v = *(const float4*)(vf + ((size_t)bh * LKE + krow) * 64 + c4 * 4);
        T[row][c4 * 4 + 0] = v.x; T[row][c4 * 4 + 1] = v.y;
        T[row][c4 * 4 + 2] = v.z; T[row][c4 * 4 + 3] = v.w;
    }
    __syncthreads();
#pragma unroll
    for (int r = 0; r < 16; r++) {
        int f = r * 256 + t;
        int d = f >> 6, key = f & 63;
        vTf[(size_t)bh * 64 * TOPK + (size_t)d * TOPK + kc + key] = T[key][d];
    }
}

// ---------------- MFMA flash attention, split-precision PV ----------------
// scores bounded in [-1,1] (q,k L2-normalized) -> no max subtraction needed.
__global__ __launch_bounds__(256) void attn_mfma_kernel(
    const unsigned short* __restrict__ qh,    // [BH][LQ][64] bf16
    const unsigned short* __restrict__ kselh, // [BH][512][64] bf16
    const float* __restrict__ vTf,            // [BH][64][512] f32
    float* __restrict__ af) {
    int bh = blockIdx.y, rt = blockIdx.x;
    int t = threadIdx.x, w = t >> 6, lane = t & 63;
    __shared__ unsigned short Qs[64 * 64];
    __shared__ unsigned short Ks[64 * 64];
    __shared__ unsigned short Vhi[64 * 64];
    __shared__ unsigned short Vlo[64 * 64];
    __shared__ unsigned short Phi[4 * 16 * 64];
    __shared__ unsigned short Plo[4 * 16 * 64];

    const unsigned short* qb = qh + ((size_t)bh * LQ + (size_t)rt * 64) * 64;
    const unsigned short* kb = kselh + (size_t)bh * TOPK * 64;
    const float* vb = vTf + (size_t)bh * 64 * TOPK;

    // stage Q (swizzled)
#pragma unroll
    for (int r = 0; r < 2; r++) {
        int c = r * 256 + t; int row = c >> 3, c8 = c & 7;
        bf16x8 v = *(const bf16x8*)(qb + row * 64 + c8 * 8);
        *(bf16x8*)((char*)Qs + ((row * 128 + c8 * 16) ^ ((row & 7) << 4))) = v;
    }
    // stage K/V(hi,lo) for chunk kc0
    auto stageKV = [&](int kc0) {
#pragma unroll
        for (int r = 0; r < 2; r++) {
            int c = r * 256 + t; int row = c >> 3, c8 = c & 7;
            int off = (row * 128 + c8 * 16) ^ ((row & 7) << 4);
            bf16x8 kv = *(const bf16x8*)(kb + (kc0 + row) * 64 + c8 * 8);
            *(bf16x8*)((char*)Ks + off) = kv;
            const float* vp = vb + (size_t)row * TOPK + kc0 + c8 * 8;
            bf16x8 hi, lo;
#pragma unroll
            for (int i = 0; i < 8; i++) {
                float v = vp[i];
                unsigned short h = f2bf(v);
                hi[i] = (short)h;
                lo[i] = (short)f2bf(v - bf2f(h));
            }
            *(bf16x8*)((char*)Vhi + off) = hi;
            *(bf16x8*)((char*)Vlo + off) = lo;
        }
    };
    stageKV(0);
    __syncthreads();

    // Q fragments (held in registers for the whole kernel)
    bf16x8 qfrag[2];
#pragma unroll
    for (int kk = 0; kk < 2; kk++) {
        int row = w * 16 + (lane & 15);
        qfrag[kk] = *(const bf16x8*)((char*)Qs +
            ((row * 128 + kk * 64 + (lane >> 4) * 16) ^ ((row & 7) << 4)));
    }

    f32x4 o[4];
#pragma unroll
    for (int m = 0; m < 4; m++) o[m] = (f32x4){0.f, 0.f, 0.f, 0.f};
    float lsum[4] = {0.f, 0.f, 0.f, 0.f};
    unsigned short* pwh = Phi + w * 16 * 64;
    unsigned short* pwl = Plo + w * 16 * 64;

    for (int ch = 0; ch < 8; ch++) {
        // S = Q K^T for 16 own q-rows x 64 keys
        f32x4 s[4];
#pragma unroll
        for (int n = 0; n < 4; n++) {
            s[n] = (f32x4){0.f, 0.f, 0.f, 0.f};
#pragma unroll
            for (int kk = 0; kk < 2; kk++) {
                int row = n * 16 + (lane & 15);
                bf16x8 kfr = *(const bf16x8*)((char*)Ks +
                    ((row * 128 + kk * 64 + (lane >> 4) * 16) ^ ((row & 7) << 4)));
                s[n] = mfma16(qfrag[kk], kfr, s[n]);
            }
        }
        // P = exp(S); per-row partial sums; store P hi/lo to LDS (swizzled)
        float part[4] = {0.f, 0.f, 0.f, 0.f};
#pragma unroll
        for (int n = 0; n < 4; n++) {
#pragma unroll
            for (int rg = 0; rg < 4; rg++) {
                float p = __expf(s[n][rg]);
                part[rg] += p;
                unsigned short ph = f2bf(p);
                unsigned short pl = f2bf(p - bf2f(ph));
                int row = (lane >> 4) * 4 + rg, col = n * 16 + (lane & 15);
                int off = (row * 128 + col * 2) ^ ((row & 7) << 4);
                *(unsigned short*)((char*)pwh + off) = ph;
                *(unsigned short*)((char*)pwl + off) = pl;
            }
        }
#pragma unroll
        for (int rg = 0; rg < 4; rg++) {
            float v = part[rg];
            v += __shfl_xor(v, 1); v += __shfl_xor(v, 2);
            v += __shfl_xor(v, 4); v += __shfl_xor(v, 8);
            lsum[rg] += v;
        }
        // P fragments (hi, lo)
        bf16x8 pfh[2], pfl[2];
#pragma unroll
        for (int kk = 0; kk < 2; kk++) {
            int row = lane & 15;
            int off = (row * 128 + kk * 64 + (lane >> 4) * 16) ^ ((row & 7) << 4);
            pfh[kk] = *(const bf16x8*)((char*)pwh + off);
            pfl[kk] = *(const bf16x8*)((char*)pwl + off);
        }
        // O += Phi*Vhi + Phi*Vlo + Plo*Vhi
#pragma unroll
        for (int m = 0; m < 4; m++) {
#pragma unroll
            for (int kk = 0; kk < 2; kk++) {
                int row = m * 16 + (lane & 15);
                int off = (row * 128 + kk * 64 + (lane >> 4) * 16) ^ ((row & 7) << 4);
                bf16x8 vh = *(const bf16x8*)((char*)Vhi + off);
                bf16x8 vl = *(const bf16x8*)((char*)Vlo + off);
                o[m] = mfma16(pfh[kk], vh, o[m]);
                o[m] = mfma16(pfh[kk], vl, o[m]);
                o[m] = mfma16(pfl[kk], vh, o[m]);
            }
        }
        if (ch < 7) {
            __syncthreads();
            stageKV((ch + 1) * 64);
            __syncthreads();
        }
    }
    // epilogue: normalize and store f32
    int row0 = w * 16 + (lane >> 4) * 4;
#pragma unroll
    for (int rg = 0; rg < 4; rg++) {
        float inv = 1.0f / lsum[rg];
        size_t base = ((size_t)bh * LQ + (size_t)rt * 64 + row0 + rg) * 64 + (lane & 15);
#pragma unroll
        for (int m = 0; m < 4; m++) af[base + m * 16] = o[m][rg] * inv;
    }
}

// ---------------- output projection GEMM (fold af -> channels) ----------------
__global__ __launch_bounds__(256) void gemm_out_kernel(
    const float* __restrict__ w, const float* __restrict__ af, float* __restrict__ pre) {
    int lt = blockIdx.x, ot = blockIdx.y, b = blockIdx.z;
    int l0 = lt * 64, o0 = ot * 64;
    __shared__ float Ws[64][33];
    __shared__ float Xs[32][65];
    __shared__ float Cs[64][65];
    int t = threadIdx.x, tx = t & 15, ty = t >> 4;
    float acc[4][4];
#pragma unroll
    for (int a = 0; a < 4; a++)
#pragma unroll
        for (int c2 = 0; c2 < 4; c2++) acc[a][c2] = 0.f;
    for (int kc = 0; kc < INNER; kc += 32) {
        int h = kc >> 6;
        int d0 = kc & 63;
#pragma unroll
        for (int r = 0; r < 8; r++) {
            int f = r * 256 + t;
            int oi = f >> 5, cj = f & 31;
            Ws[oi][cj] = w[(size_t)(o0 + oi) * INNER + kc + cj];
        }
#pragma unroll
        for (int r = 0; r < 8; r++) {
            int f = r * 256 + t;
            int lj = f >> 5, cj = f & 31;
            Xs[cj][lj] = af[((size_t)(b * HEADS + h) * LQ + l0 + lj) * 64 + d0 + cj];
        }
        __syncthreads();
#pragma unroll
        for (int kj = 0; kj < 32; kj++) {
            float wr[4], xr[4];
#pragma unroll
            for (int a = 0; a < 4; a++) wr[a] = Ws[ty * 4 + a][kj];
#pragma unroll
            for (int c2 = 0; c2 < 4; c2++) xr[c2] = Xs[kj][tx * 4 + c2];
#pragma unroll
            for (int a = 0; a < 4; a++)
#pragma unroll
                for (int c2 = 0; c2 < 4; c2++) acc[a][c2] += wr[a] * xr[c2];
        }
        __syncthreads();
    }
#pragma unroll
    for (int a = 0; a < 4; a++)
#pragma unroll
        for (int c2 = 0; c2 < 4; c2++) Cs[ty * 4 + a][tx * 4 + c2] = acc[a][c2];
    __syncthreads();
#pragma unroll
    for (int r = 0; r < 16; r++) {
        int f = r * 256 + t;
        int lj = f & 63, oi = f >> 6;
        pre[((size_t)(b * DIMC + o0 + oi)) * LQ + l0 + lj] = Cs[oi][lj];
    }
}

// ---------------- final LN + gamma*x + residual ----------------
__global__ void final_kernel(const float* __restrict__ pre, const float* __restrict__ mu,
                             const float* __restrict__ rs, const float* __restrict__ g,
                             const float* __restrict__ beta, const float* __restrict__ gamma,
                             const float* __restrict__ qs_in, float* __restrict__ out) {
    size_t idx = (size_t)blockIdx.x * 256 + threadIdx.x;
    int l = (int)(idx & (LQ - 1));
    int o = (int)((idx >> 14) & 255);
    int b = (int)(idx >> 22);
    int loc = b * LQ + l;
    float xn = (pre[idx] - mu[loc]) * rs[loc] * g[o] + beta[o];
    out[idx] = gamma[0] * xn + qs_in[idx];
}

extern "C" void kernel_launch(void* const* d_in, const int* in_sizes, int n_in,
                              void* d_out, int out_size, void* d_ws, size_t ws_size,
                              hipStream_t stream) {
    const float* qs_in = (const float*)d_in[0];
    const float* ctx   = (const float*)d_in[1];
    const int*   ridx  = (const int*)d_in[2];
    const float* g_ctx = (const float*)d_in[3];
    const float* b_ctx = (const float*)d_in[4];
    const float* g_qs  = (const float*)d_in[5];
    const float* b_qs  = (const float*)d_in[6];
    const float* w_kv  = (const float*)d_in[7];
    const float* w_q   = (const float*)d_in[8];
    const float* w_out = (const float*)d_in[9];
    const float* g_out = (const float*)d_in[10];
    const float* b_out = (const float*)d_in[11];
    const float* gamma = (const float*)d_in[12];
    float* out = (float*)d_out;

    char* ws = (char*)d_ws;
    size_t off = 0;
    auto alloc = [&](size_t bytes) { char* p = ws + off; off += (bytes + 255) & ~(size_t)255; return p; };

    float*          kf    = (float*)alloc((size_t)NBH * LKE * 64 * 4);
    float*          vf    = (float*)alloc((size_t)NBH * LKE * 64 * 4);
    unsigned short* qh    = (unsigned short*)alloc((size_t)NBH * LQ * 64 * 2);
    float*          af    = (float*)alloc((size_t)NBH * LQ * 64 * 4);
    float*          Qsm   = (float*)alloc((size_t)NBH * TOPK * 64 * 4);
    unsigned short* kselh = (unsigned short*)alloc((size_t)NBH * TOPK * 64 * 2);
    float*          vTf   = (float*)alloc((size_t)NBH * 64 * TOPK * 4);
    float*          pre   = (float*)alloc((size_t)NB * DIMC * LQ * 4);
    float*          min_d = (float*)alloc((size_t)NBH * LKE * 4);
    float*          mu_c  = (float*)alloc(NB * LKE * 4);
    float*          rs_c  = (float*)alloc(NB * LKE * 4);
    float*          mu_q  = (float*)alloc(NB * LQ * 4);
    float*          rs_q  = (float*)alloc(NB * LQ * 4);
    float*          mu_o  = (float*)alloc(NB * LQ * 4);
    float*          rs_o  = (float*)alloc(NB * LQ * 4);
    int*            isel  = (int*)alloc(NBH * TOPK * 4);

    stats_kernel<<<(NB * LKE + 255) / 256, 256, 0, stream>>>(ctx, mu_c, rs_c, LKE, NB * LKE);
    stats_kernel<<<(NB * LQ + 255) / 256, 256, 0, stream>>>(qs_in, mu_q, rs_q, LQ, NB * LQ);
    gemm_proj_kernel<false><<<dim3(LKE / 64, 16, NB), 256, 0, stream>>>(
        w_kv, ctx, mu_c, rs_c, g_ctx, b_ctx, LKE, 8, kf, vf);
    gemm_proj_kernel<true><<<dim3(LQ / 64, 8, NB), 256, 0, stream>>>(
        w_q, qs_in, mu_q, rs_q, g_qs, b_qs, LQ, 8, qh, qh);
    qsample_kernel<<<dim3(TOPK / 64, NBH), 256, 0, stream>>>(
        qs_in, mu_q, rs_q, g_qs, b_qs, w_q, ridx, Qsm);
    cdist_min_kernel<<<dim3(LKE / 64, NBH), 256, 0, stream>>>(kf, Qsm, min_d);
    select_topk_kernel<<<NBH, 256, 0, stream>>>(min_d, isel);
    gather_k_kernel<<<(NBH * TOPK * 64) / 256, 256, 0, stream>>>(kf, isel, kselh);
    gather_vT_kernel<<<dim3(TOPK / 64, NBH), 256, 0, stream>>>(vf, isel, vTf);
    attn_mfma_kernel<<<dim3(LQ / 64, NBH), 256, 0, stream>>>(qh, kselh, vTf, af);
    gemm_out_kernel<<<dim3(LQ / 64, DIMC / 64, NB), 256, 0, stream>>>(w_out, af, pre);
    stats_kernel<<<(NB * LQ + 255) / 256, 256, 0, stream>>>(pre, mu_o, rs_o, LQ, NB * LQ);
    final_kernel<<<(NB * DIMC * LQ) / 256, 256, 0, stream>>>(
        pre, mu_o, rs_o, g_out, b_out, gamma, qs_in, out);
}

// Round 4
// 526.316 us; speedup vs baseline: 3.6243x; 1.6396x over previous
//
#include <hip/hip_runtime.h>
#include <hip/hip_bf16.h>
#include <math.h>

#define DIMC  256
#define HEADS 8
#define DH    64
#define INNER 512
#define TOPK  512
#define LQ    16384
#define LKE   4096
#define NB    2
#define NBH   16

typedef __attribute__((ext_vector_type(8))) short bf16x8;
typedef __attribute__((ext_vector_type(4))) float f32x4;

__device__ __forceinline__ unsigned short f2bf(float f) {
    unsigned u = __float_as_uint(f);
    u += 0x7FFFu + ((u >> 16) & 1u);
    return (unsigned short)(u >> 16);
}
__device__ __forceinline__ float bf2f(unsigned short b) {
    return __uint_as_float(((unsigned)b) << 16);
}
__device__ __forceinline__ f32x4 mfma16(bf16x8 a, bf16x8 b, f32x4 c) {
    return __builtin_amdgcn_mfma_f32_16x16x32_bf16(a, b, c, 0, 0, 0);
}

// ---------------- channel-LN stats: one thread per (b,l) ----------------
__global__ void stats_kernel(const float* __restrict__ x, float* __restrict__ mu,
                             float* __restrict__ rs, int L, int total) {
    int idx = blockIdx.x * 256 + threadIdx.x;
    if (idx >= total) return;
    int b = idx / L, l = idx - b * L;
    const float* p = x + (size_t)b * DIMC * L + l;
    float s = 0.f, sq = 0.f;
    for (int c = 0; c < DIMC; c++) {
        float v = p[(size_t)c * L];
        s += v; sq += v * v;
    }
    float m = s * (1.0f / DIMC);
    float var = fmaxf(sq * (1.0f / DIMC) - m * m, 0.f);
    mu[idx] = m;
    rs[idx] = rsqrtf(var + 1e-5f);
}

// ------- LN + transpose to [b][L][C], split into bf16 hi/lo planes -------
__global__ __launch_bounds__(256) void ln_transpose_kernel(
    const float* __restrict__ x, const float* __restrict__ mu, const float* __restrict__ rs,
    const float* __restrict__ g, const float* __restrict__ beta, int L,
    unsigned short* __restrict__ xhi, unsigned short* __restrict__ xlo) {
    int lt = blockIdx.x, ct = blockIdx.y, b = blockIdx.z;
    int l0 = lt * 64, c0 = ct * 64;
    int t = threadIdx.x;
    __shared__ float T[64][65];
#pragma unroll
    for (int r = 0; r < 16; r++) {
        int f = r * 256 + t;
        int l = f & 63, c = f >> 6;
        int loc = b * L + l0 + l;
        float v = x[((size_t)b * DIMC + c0 + c) * L + l0 + l];
        T[c][l] = (v - mu[loc]) * rs[loc] * g[c0 + c] + beta[c0 + c];
    }
    __syncthreads();
#pragma unroll
    for (int r = 0; r < 16; r++) {
        int f = r * 256 + t;
        int c = f & 63, l = f >> 6;
        float v = T[c][l];
        unsigned short hi = f2bf(v);
        size_t di = ((size_t)b * L + l0 + l) * DIMC + c0 + c;
        xhi[di] = hi;
        xlo[di] = f2bf(v - bf2f(hi));
    }
}

// ------------- split-bf16 MFMA GEMM, 128x128 tile, fused epilogues -------------
// MODE 0: KV proj  (M=1024,K=256,N=LKE)  rows<512 -> kf (L2norm), rows>=512 -> vf
// MODE 1: Q  proj  (M=512, K=256,N=LQ)   all rows L2norm -> qh bf16
// MODE 2: OUT      (M=256, K=512,N=LQ)   -> pre [b][l][256] f32
template<int MODE>
__global__ __launch_bounds__(256) void gemm_mfma_kernel(
    const float* __restrict__ wmat,
    const unsigned short* __restrict__ xhi, const unsigned short* __restrict__ xlo,
    void* __restrict__ dst0, void* __restrict__ dst1) {
    constexpr int K = (MODE == 2) ? 512 : 256;
    constexpr int N = (MODE == 0) ? LKE : LQ;
    int n0 = blockIdx.x * 128;
    int by = blockIdx.y;
    int bb = blockIdx.z;
    int t = threadIdx.x, w = t >> 6, lane = t & 63;
    int wm = w >> 1, wn = w & 1;
    int lanelo = lane & 15, lanehi = lane >> 4;

    __shared__ __align__(16) char Wh[16384];
    __shared__ __align__(16) char Wl[16384];
    __shared__ __align__(16) char Xh[16384];
    __shared__ __align__(16) char Xl[16384];

    const float* wsrc = wmat + (size_t)by * 128 * K;
    const unsigned short* xsh = xhi + ((size_t)bb * N + n0) * K;
    const unsigned short* xsl = xlo + ((size_t)bb * N + n0) * K;

    f32x4 acc[4][4];
#pragma unroll
    for (int mi = 0; mi < 4; mi++)
#pragma unroll
        for (int ni = 0; ni < 4; ni++) acc[mi][ni] = (f32x4){0.f, 0.f, 0.f, 0.f};

    for (int k0 = 0; k0 < K; k0 += 64) {
        if (k0) __syncthreads();
#pragma unroll
        for (int gg = 0; gg < 4; gg++) {
            int e = gg * 2048 + t * 8;
            int row = e >> 6, kc = e & 63;
            const float* wp = wsrc + (size_t)row * K + k0 + kc;
            bf16x8 hi, lo;
#pragma unroll
            for (int i = 0; i < 8; i++) {
                float v = wp[i];
                unsigned short h = f2bf(v);
                hi[i] = (short)h;
                lo[i] = (short)f2bf(v - bf2f(h));
            }
            int off = (row * 128 + kc * 2) ^ ((row & 7) << 4);
            *(bf16x8*)(Wh + off) = hi;
            *(bf16x8*)(Wl + off) = lo;
            *(bf16x8*)(Xh + off) = *(const bf16x8*)(xsh + (size_t)row * K + k0 + kc);
            *(bf16x8*)(Xl + off) = *(const bf16x8*)(xsl + (size_t)row * K + k0 + kc);
        }
        __syncthreads();
#pragma unroll
        for (int kk = 0; kk < 2; kk++) {
            bf16x8 ah[4], al[4], bh_[4], bl_[4];
#pragma unroll
            for (int mi = 0; mi < 4; mi++) {
                int row = wm * 64 + mi * 16 + lanelo;
                int off = (row * 128 + kk * 64 + lanehi * 16) ^ ((row & 7) << 4);
                ah[mi] = *(const bf16x8*)(Wh + off);
                al[mi] = *(const bf16x8*)(Wl + off);
            }
#pragma unroll
            for (int ni = 0; ni < 4; ni++) {
                int row = wn * 64 + ni * 16 + lanelo;
                int off = (row * 128 + kk * 64 + lanehi * 16) ^ ((row & 7) << 4);
                bh_[ni] = *(const bf16x8*)(Xh + off);
                bl_[ni] = *(const bf16x8*)(Xl + off);
            }
#pragma unroll
            for (int mi = 0; mi < 4; mi++)
#pragma unroll
                for (int ni = 0; ni < 4; ni++) {
                    acc[mi][ni] = mfma16(ah[mi], bh_[ni], acc[mi][ni]);
                    acc[mi][ni] = mfma16(ah[mi], bl_[ni], acc[mi][ni]);
                    acc[mi][ni] = mfma16(al[mi], bh_[ni], acc[mi][ni]);
                }
        }
    }

    // epilogue
    bool donorm = (MODE == 1) || (MODE == 0 && by < 4);
    float inv[4];
    if (donorm) {
#pragma unroll
        for (int ni = 0; ni < 4; ni++) {
            float s = 0.f;
#pragma unroll
            for (int mi = 0; mi < 4; mi++)
#pragma unroll
                for (int rg = 0; rg < 4; rg++) s += acc[mi][ni][rg] * acc[mi][ni][rg];
            s += __shfl_xor(s, 16);
            s += __shfl_xor(s, 32);
            inv[ni] = 1.0f / fmaxf(sqrtf(s), 1e-12f);
        }
    }
#pragma unroll
    for (int mi = 0; mi < 4; mi++) {
        int rowg = by * 128 + wm * 64 + mi * 16 + lanehi * 4;
#pragma unroll
        for (int ni = 0; ni < 4; ni++) {
            int l = n0 + wn * 64 + ni * 16 + lanelo;
            if (MODE == 0) {
                bool isk = rowg < 512;
                float sc = isk ? inv[ni] : 1.0f;
                int h = (rowg >> 6) & 7, d0 = rowg & 63;
                float4 v = make_float4(acc[mi][ni][0] * sc, acc[mi][ni][1] * sc,
                                       acc[mi][ni][2] * sc, acc[mi][ni][3] * sc);
                float* dp = isk ? (float*)dst0 : (float*)dst1;
                *(float4*)&dp[((size_t)(bb * HEADS + h) * LKE + l) * 64 + d0] = v;
            } else if (MODE == 1) {
                int h = rowg >> 6, d0 = rowg & 63;
                ushort4 u;
                u.x = f2bf(acc[mi][ni][0] * inv[ni]);
                u.y = f2bf(acc[mi][ni][1] * inv[ni]);
                u.z = f2bf(acc[mi][ni][2] * inv[ni]);
                u.w = f2bf(acc[mi][ni][3] * inv[ni]);
                unsigned short* qp = (unsigned short*)dst0;
                *(ushort4*)&qp[((size_t)(bb * HEADS + h) * LQ + l) * 64 + d0] = u;
            } else {
                float4 v = make_float4(acc[mi][ni][0], acc[mi][ni][1],
                                       acc[mi][ni][2], acc[mi][ni][3]);
                float* pp = (float*)dst0;
                *(float4*)&pp[((size_t)bb * LQ + l) * 256 + rowg] = v;
            }
        }
    }
}

// ------- exact f32 sampled-query recompute: LN -> w_q proj -> l2norm ---------
__global__ __launch_bounds__(256) void qsample_kernel(
    const float* __restrict__ x, const float* __restrict__ mu, const float* __restrict__ rs,
    const float* __restrict__ g, const float* __restrict__ beta,
    const float* __restrict__ w, const int* __restrict__ ridx,
    float* __restrict__ Qsm) {
    int lt = blockIdx.x, bh = blockIdx.y;
    int b = bh >> 3, h = bh & 7;
    int t = threadIdx.x, tx = t & 15, ty = t >> 4;
    __shared__ float Ws[64][33];
    __shared__ float Xs[32][65];
    __shared__ float Cs[64][65];
    __shared__ float nf[64];
    __shared__ int lidx[64];
    if (t < 64) lidx[t] = ridx[bh * TOPK + lt * 64 + t];
    __syncthreads();
    float acc[4][4];
#pragma unroll
    for (int a = 0; a < 4; a++)
#pragma unroll
        for (int c2 = 0; c2 < 4; c2++) acc[a][c2] = 0.f;
    for (int kc = 0; kc < DIMC; kc += 32) {
#pragma unroll
        for (int r = 0; r < 8; r++) {
            int f = r * 256 + t;
            int oi = f >> 5, kj = f & 31;
            Ws[oi][kj] = w[(size_t)(h * 64 + oi) * DIMC + kc + kj];
        }
#pragma unroll
        for (int r = 0; r < 8; r++) {
            int f = r * 256 + t;
            int kj = f >> 6, lj = f & 63;
            int l = lidx[lj];
            int loc = b * LQ + l;
            float v = x[(size_t)b * DIMC * LQ + (size_t)(kc + kj) * LQ + l];
            Xs[kj][lj] = (v - mu[loc]) * rs[loc] * g[kc + kj] + beta[kc + kj];
        }
        __syncthreads();
#pragma unroll
        for (int kj = 0; kj < 32; kj++) {
            float wr[4], xr[4];
#pragma unroll
            for (int a = 0; a < 4; a++) wr[a] = Ws[ty * 4 + a][kj];
#pragma unroll
            for (int c2 = 0; c2 < 4; c2++) xr[c2] = Xs[kj][tx * 4 + c2];
#pragma unroll
            for (int a = 0; a < 4; a++)
#pragma unroll
                for (int c2 = 0; c2 < 4; c2++) acc[a][c2] += wr[a] * xr[c2];
        }
        __syncthreads();
    }
#pragma unroll
    for (int a = 0; a < 4; a++)
#pragma unroll
        for (int c2 = 0; c2 < 4; c2++) Cs[ty * 4 + a][tx * 4 + c2] = acc[a][c2];
    __syncthreads();
    if (t < 64) {
        float sq = 0.f;
        for (int o = 0; o < 64; o++) { float v = Cs[o][t]; sq += v * v; }
        nf[t] = 1.0f / fmaxf(sqrtf(sq), 1e-12f);
    }
    __syncthreads();
#pragma unroll
    for (int r = 0; r < 16; r++) {
        int f = r * 256 + t;
        int d = f & 63, lj = f >> 6;
        Qsm[((size_t)bh * TOPK + (size_t)lt * 64 + lj) * 64 + d] = Cs[d][lj] * nf[lj];
    }
}

// ---------------- L1 cdist + min over sampled queries ----------------
__global__ __launch_bounds__(256) void cdist_min_kernel(
    const float* __restrict__ kf, const float* __restrict__ Qsm,
    float* __restrict__ min_d) {
    int bh = blockIdx.y, kt = blockIdx.x;
    int t = threadIdx.x;
    int i = t & 63, jg = t >> 6;
    __shared__ float Ks[64][65];
    __shared__ float Qc[64][68];   // [d][j]
    __shared__ float part[4][64];
    const float* kbase = kf + ((size_t)bh * LKE + (size_t)kt * 64) * 64;
#pragma unroll
    for (int rr = 0; rr < 16; rr++) {
        int f = rr * 256 + t;
        int row = f >> 6, d = f & 63;
        Ks[row][d] = kbase[(size_t)row * 64 + d];
    }
    float best = 3.0e38f;
    const float* qb = Qsm + (size_t)bh * TOPK * 64;
    for (int qc = 0; qc < TOPK; qc += 64) {
        __syncthreads();
#pragma unroll
        for (int rr = 0; rr < 16; rr++) {
            int f = rr * 256 + t;
            int j = f >> 6, d = f & 63;
            Qc[d][j] = qb[(size_t)(qc + j) * 64 + d];
        }
        __syncthreads();
        float acc[16];
#pragma unroll
        for (int jj = 0; jj < 16; jj++) acc[jj] = 0.f;
#pragma unroll 4
        for (int d = 0; d < 64; d++) {
            float kd = Ks[i][d];
            const float4* qr = (const float4*)&Qc[d][jg * 16];
            float4 a0 = qr[0], a1 = qr[1], a2 = qr[2], a3 = qr[3];
            acc[0]  += fabsf(kd - a0.x); acc[1]  += fabsf(kd - a0.y);
            acc[2]  += fabsf(kd - a0.z); acc[3]  += fabsf(kd - a0.w);
            acc[4]  += fabsf(kd - a1.x); acc[5]  += fabsf(kd - a1.y);
            acc[6]  += fabsf(kd - a1.z); acc[7]  += fabsf(kd - a1.w);
            acc[8]  += fabsf(kd - a2.x); acc[9]  += fabsf(kd - a2.y);
            acc[10] += fabsf(kd - a2.z); acc[11] += fabsf(kd - a2.w);
            acc[12] += fabsf(kd - a3.x); acc[13] += fabsf(kd - a3.y);
            acc[14] += fabsf(kd - a3.z); acc[15] += fabsf(kd - a3.w);
        }
#pragma unroll
        for (int jj = 0; jj < 16; jj++) best = fminf(best, acc[jj]);
    }
    part[jg][i] = best;
    __syncthreads();
    if (t < 64) {
        float v = fminf(fminf(part[0][t], part[1][t]), fminf(part[2][t], part[3][t]));
        min_d[(size_t)bh * LKE + (size_t)kt * 64 + t] = v;
    }
}

// ---------------- radix-select 512 smallest per row (deterministic) ----------
__global__ void select_topk_kernel(const float* __restrict__ min_d, int* __restrict__ isel) {
    int bh = blockIdx.x;
    int t = threadIdx.x;  // 256
    __shared__ unsigned su[LKE];
    __shared__ int hist[256];
    __shared__ int sb[2];
    for (int i = t; i < LKE; i += 256)
        su[i] = __float_as_uint(min_d[(size_t)bh * LKE + i]);
    unsigned prefix = 0, mask = 0;
    int need = TOPK;
    for (int shift = 24; shift >= 0; shift -= 8) {
        hist[t] = 0;
        __syncthreads();
        for (int i = t; i < LKE; i += 256) {
            unsigned u = su[i];
            if ((u & mask) == prefix) atomicAdd(&hist[(u >> shift) & 255], 1);
        }
        __syncthreads();
        if (t == 0) {
            int c = 0, bsel = 0;
            for (; bsel < 255; bsel++) {
                if (c + hist[bsel] >= need) break;
                c += hist[bsel];
            }
            sb[0] = bsel; sb[1] = need - c;
        }
        __syncthreads();
        prefix |= ((unsigned)sb[0]) << shift;
        mask |= (255u << shift);
        need = sb[1];
        __syncthreads();
    }
    if (t < 64) {
        int pos = 0, eqseen = 0;
        unsigned long long lanem1 = (t == 0) ? 0ull : ((1ull << t) - 1ull);
        for (int i0 = 0; i0 < LKE; i0 += 64) {
            unsigned u = su[i0 + t];
            bool lt = (u < prefix);
            bool eq = (u == prefix);
            unsigned long long be = __ballot(eq);
            int eqbefore = __popcll(be & lanem1);
            bool take = lt || (eq && (eqseen + eqbefore) < need);
            unsigned long long bt = __ballot(take);
            if (take) isel[bh * TOPK + pos + __popcll(bt & lanem1)] = i0 + t;
            pos += __popcll(bt);
            eqseen += __popcll(be);
        }
    }
}

// ---------------- gather selected K (f32 -> bf16, [bh][key][d]) ----------------
__global__ void gather_k_kernel(const float* __restrict__ kf, const int* __restrict__ isel,
                                unsigned short* __restrict__ kselh) {
    int idx = blockIdx.x * 256 + threadIdx.x;
    int d = idx & 63;
    int ti = (idx >> 6) & (TOPK - 1);
    int bh = idx >> 15;
    int row = isel[bh * TOPK + ti];
    kselh[idx] = f2bf(kf[((size_t)bh * LKE + row) * 64 + d]);
}

// ---------------- gather selected V transposed (f32, [bh][d][key]) ------
__global__ __launch_bounds__(256) void gather_vT_kernel(
    const float* __restrict__ vf, const int* __restrict__ isel,
    float* __restrict__ vTf) {
    int bh = blockIdx.y, kc = blockIdx.x * 64;
    int t = threadIdx.x;
    __shared__ float T[64][65];
#pragma unroll
    for (int r = 0; r < 4; r++) {
        int c = r * 256 + t;          // 1024 float4 chunks
        int row = c >> 4, c4 = c & 15;
        int krow = isel[bh * TOPK + kc + row];
        float4 v = *(const float4*)(vf + ((size_t)bh * LKE + krow) * 64 + c4 * 4);
        T[row][c4 * 4 + 0] = v.x; T[row][c4 * 4 + 1] = v.y;
        T[row][c4 * 4 + 2] = v.z; T[row][c4 * 4 + 3] = v.w;
    }
    __syncthreads();
#pragma unroll
    for (int r = 0; r < 16; r++) {
        int f = r * 256 + t;
        int d = f >> 6, key = f & 63;
        vTf[(size_t)bh * 64 * TOPK + (size_t)d * TOPK + kc + key] = T[key][d];
    }
}

// ---------------- MFMA flash attention, split-precision PV ----------------
__global__ __launch_bounds__(256) void attn_mfma_kernel(
    const unsigned short* __restrict__ qh,    // [BH][LQ][64] bf16
    const unsigned short* __restrict__ kselh, // [BH][512][64] bf16
    const float* __restrict__ vTf,            // [BH][64][512] f32
    unsigned short* __restrict__ afT_hi,      // [b][LQ][512]
    unsigned short* __restrict__ afT_lo) {
    int bh = blockIdx.y, rt = blockIdx.x;
    int bq = bh >> 3, h = bh & 7;
    int t = threadIdx.x, w = t >> 6, lane = t & 63;
    __shared__ unsigned short Qs[64 * 64];
    __shared__ unsigned short Ks[64 * 64];
    __shared__ unsigned short Vhi[64 * 64];
    __shared__ unsigned short Vlo[64 * 64];
    __shared__ unsigned short Phi[4 * 16 * 64];
    __shared__ unsigned short Plo[4 * 16 * 64];

    const unsigned short* qb = qh + ((size_t)bh * LQ + (size_t)rt * 64) * 64;
    const unsigned short* kb = kselh + (size_t)bh * TOPK * 64;
    const float* vb = vTf + (size_t)bh * 64 * TOPK;

#pragma unroll
    for (int r = 0; r < 2; r++) {
        int c = r * 256 + t; int row = c >> 3, c8 = c & 7;
        bf16x8 v = *(const bf16x8*)(qb + row * 64 + c8 * 8);
        *(bf16x8*)((char*)Qs + ((row * 128 + c8 * 16) ^ ((row & 7) << 4))) = v;
    }
    auto stageKV = [&](int kc0) {
#pragma unroll
        for (int r = 0; r < 2; r++) {
            int c = r * 256 + t; int row = c >> 3, c8 = c & 7;
            int off = (row * 128 + c8 * 16) ^ ((row & 7) << 4);
            bf16x8 kv = *(const bf16x8*)(kb + (kc0 + row) * 64 + c8 * 8);
            *(bf16x8*)((char*)Ks + off) = kv;
            const float* vp = vb + (size_t)row * TOPK + kc0 + c8 * 8;
            bf16x8 hi, lo;
#pragma unroll
            for (int i = 0; i < 8; i++) {
                float v = vp[i];
                unsigned short hh = f2bf(v);
                hi[i] = (short)hh;
                lo[i] = (short)f2bf(v - bf2f(hh));
            }
            *(bf16x8*)((char*)Vhi + off) = hi;
            *(bf16x8*)((char*)Vlo + off) = lo;
        }
    };
    stageKV(0);
    __syncthreads();

    bf16x8 qfrag[2];
#pragma unroll
    for (int kk = 0; kk < 2; kk++) {
        int row = w * 16 + (lane & 15);
        qfrag[kk] = *(const bf16x8*)((char*)Qs +
            ((row * 128 + kk * 64 + (lane >> 4) * 16) ^ ((row & 7) << 4)));
    }

    f32x4 o[4];
#pragma unroll
    for (int m = 0; m < 4; m++) o[m] = (f32x4){0.f, 0.f, 0.f, 0.f};
    float lsum[4] = {0.f, 0.f, 0.f, 0.f};
    unsigned short* pwh = Phi + w * 16 * 64;
    unsigned short* pwl = Plo + w * 16 * 64;

    for (int ch = 0; ch < 8; ch++) {
        f32x4 s[4];
#pragma unroll
        for (int n = 0; n < 4; n++) {
            s[n] = (f32x4){0.f, 0.f, 0.f, 0.f};
#pragma unroll
            for (int kk = 0; kk < 2; kk++) {
                int row = n * 16 + (lane & 15);
                bf16x8 kfr = *(const bf16x8*)((char*)Ks +
                    ((row * 128 + kk * 64 + (lane >> 4) * 16) ^ ((row & 7) << 4)));
                s[n] = mfma16(qfrag[kk], kfr, s[n]);
            }
        }
        float part[4] = {0.f, 0.f, 0.f, 0.f};
#pragma unroll
        for (int n = 0; n < 4; n++) {
#pragma unroll
            for (int rg = 0; rg < 4; rg++) {
                float p = __expf(s[n][rg]);
                part[rg] += p;
                unsigned short ph = f2bf(p);
                unsigned short pl = f2bf(p - bf2f(ph));
                int row = (lane >> 4) * 4 + rg, col = n * 16 + (lane & 15);
                int off = (row * 128 + col * 2) ^ ((row & 7) << 4);
                *(unsigned short*)((char*)pwh + off) = ph;
                *(unsigned short*)((char*)pwl + off) = pl;
            }
        }
#pragma unroll
        for (int rg = 0; rg < 4; rg++) {
            float v = part[rg];
            v += __shfl_xor(v, 1); v += __shfl_xor(v, 2);
            v += __shfl_xor(v, 4); v += __shfl_xor(v, 8);
            lsum[rg] += v;
        }
        bf16x8 pfh[2], pfl[2];
#pragma unroll
        for (int kk = 0; kk < 2; kk++) {
            int row = lane & 15;
            int off = (row * 128 + kk * 64 + (lane >> 4) * 16) ^ ((row & 7) << 4);
            pfh[kk] = *(const bf16x8*)((char*)pwh + off);
            pfl[kk] = *(const bf16x8*)((char*)pwl + off);
        }
#pragma unroll
        for (int m = 0; m < 4; m++) {
#pragma unroll
            for (int kk = 0; kk < 2; kk++) {
                int row = m * 16 + (lane & 15);
                int off = (row * 128 + kk * 64 + (lane >> 4) * 16) ^ ((row & 7) << 4);
                bf16x8 vh = *(const bf16x8*)((char*)Vhi + off);
                bf16x8 vl = *(const bf16x8*)((char*)Vlo + off);
                o[m] = mfma16(pfh[kk], vh, o[m]);
                o[m] = mfma16(pfh[kk], vl, o[m]);
                o[m] = mfma16(pfl[kk], vh, o[m]);
            }
        }
        if (ch < 7) {
            __syncthreads();
            stageKV((ch + 1) * 64);
            __syncthreads();
        }
    }
    int row0 = w * 16 + (lane >> 4) * 4;
#pragma unroll
    for (int rg = 0; rg < 4; rg++) {
        float invs = 1.0f / lsum[rg];
        int l = rt * 64 + row0 + rg;
        size_t base = ((size_t)bq * LQ + l) * 512 + h * 64 + (lane & 15);
#pragma unroll
        for (int m = 0; m < 4; m++) {
            float v = o[m][rg] * invs;
            unsigned short hb = f2bf(v);
            afT_hi[base + m * 16] = hb;
            afT_lo[base + m * 16] = f2bf(v - bf2f(hb));
        }
    }
}

// ---------------- per-location stats over 256 channels (pre is [b][l][256]) ----
__global__ void stats_loc_kernel(const float* __restrict__ pre, float* __restrict__ mu,
                                 float* __restrict__ rs) {
    int t = threadIdx.x;
    int grp = t >> 4, ln = t & 15;
    int loc = blockIdx.x * 16 + grp;
    const float4* p = (const float4*)(pre + (size_t)loc * 256);
    float s = 0.f, sq = 0.f;
#pragma unroll
    for (int i = 0; i < 4; i++) {
        float4 v = p[ln + i * 16];
        s += v.x + v.y + v.z + v.w;
        sq += v.x * v.x + v.y * v.y + v.z * v.z + v.w * v.w;
    }
#pragma unroll
    for (int d = 1; d < 16; d <<= 1) {
        s += __shfl_xor(s, d);
        sq += __shfl_xor(sq, d);
    }
    if (ln == 0) {
        float m = s * (1.0f / 256.0f);
        float var = fmaxf(sq * (1.0f / 256.0f) - m * m, 0.f);
        mu[loc] = m;
        rs[loc] = rsqrtf(var + 1e-5f);
    }
}

// ---------------- final LN + gamma*x + residual (transpose to [b][ch][l]) ------
__global__ __launch_bounds__(256) void final_kernel(
    const float* __restrict__ pre, const float* __restrict__ mu,
    const float* __restrict__ rs, const float* __restrict__ g,
    const float* __restrict__ beta, const float* __restrict__ gamma,
    const float* __restrict__ qs_in, float* __restrict__ out) {
    int lt = blockIdx.x, ot = blockIdx.y, b = blockIdx.z;
    int l0 = lt * 64, o0 = ot * 64;
    int t = threadIdx.x;
    __shared__ float T[64][65];
    float gm = gamma[0];
#pragma unroll
    for (int r = 0; r < 16; r++) {
        int f = r * 256 + t;
        int o = f & 63, l = f >> 6;
        int loc = b * LQ + l0 + l;
        float v = pre[(size_t)loc * 256 + o0 + o];
        T[o][l] = ((v - mu[loc]) * rs[loc] * g[o0 + o] + beta[o0 + o]) * gm;
    }
    __syncthreads();
#pragma unroll
    for (int r = 0; r < 16; r++) {
        int f = r * 256 + t;
        int l = f & 63, o = f >> 6;
        size_t oi = ((size_t)(b * DIMC + o0 + o)) * LQ + l0 + l;
        out[oi] = T[o][l] + qs_in[oi];
    }
}

extern "C" void kernel_launch(void* const* d_in, const int* in_sizes, int n_in,
                              void* d_out, int out_size, void* d_ws, size_t ws_size,
                              hipStream_t stream) {
    const float* qs_in = (const float*)d_in[0];
    const float* ctx   = (const float*)d_in[1];
    const int*   ridx  = (const int*)d_in[2];
    const float* g_ctx = (const float*)d_in[3];
    const float* b_ctx = (const float*)d_in[4];
    const float* g_qs  = (const float*)d_in[5];
    const float* b_qs  = (const float*)d_in[6];
    const float* w_kv  = (const float*)d_in[7];
    const float* w_q   = (const float*)d_in[8];
    const float* w_out = (const float*)d_in[9];
    const float* g_out = (const float*)d_in[10];
    const float* b_out = (const float*)d_in[11];
    const float* gamma = (const float*)d_in[12];
    float* out = (float*)d_out;

    char* ws = (char*)d_ws;
    size_t off = 0;
    auto alloc = [&](size_t bytes) { char* p = ws + off; off += (bytes + 255) & ~(size_t)255; return p; };

    float*          kf    = (float*)alloc((size_t)NBH * LKE * 64 * 4);
    float*          vf    = (float*)alloc((size_t)NBH * LKE * 64 * 4);
    unsigned short* qh    = (unsigned short*)alloc((size_t)NBH * LQ * 64 * 2);
    // union region: {ctxT_hi, ctxT_lo, qsT_hi, qsT_lo} (early) / {afT_hi, afT_lo} (late)
    char*           uni   = alloc((size_t)2 * NB * LQ * INNER * 2);
    unsigned short* ctxT_hi = (unsigned short*)(uni);
    unsigned short* ctxT_lo = (unsigned short*)(uni + (size_t)NB * LKE * DIMC * 2);
    unsigned short* qsT_hi  = (unsigned short*)(uni + (size_t)2 * NB * LKE * DIMC * 2);
    unsigned short* qsT_lo  = (unsigned short*)(uni + (size_t)2 * NB * LKE * DIMC * 2 + (size_t)NB * LQ * DIMC * 2);
    unsigned short* afT_hi  = (unsigned short*)(uni);
    unsigned short* afT_lo  = (unsigned short*)(uni + (size_t)NB * LQ * INNER * 2);

    float*          Qsm   = (float*)alloc((size_t)NBH * TOPK * 64 * 4);
    unsigned short* kselh = (unsigned short*)alloc((size_t)NBH * TOPK * 64 * 2);
    float*          vTf   = (float*)alloc((size_t)NBH * 64 * TOPK * 4);
    float*          pre   = (float*)alloc((size_t)NB * LQ * DIMC * 4);
    float*          min_d = (float*)alloc((size_t)NBH * LKE * 4);
    float*          mu_c  = (float*)alloc(NB * LKE * 4);
    float*          rs_c  = (float*)alloc(NB * LKE * 4);
    float*          mu_q  = (float*)alloc(NB * LQ * 4);
    float*          rs_q  = (float*)alloc(NB * LQ * 4);
    float*          mu_o  = (float*)alloc(NB * LQ * 4);
    float*          rs_o  = (float*)alloc(NB * LQ * 4);
    int*            isel  = (int*)alloc(NBH * TOPK * 4);

    stats_kernel<<<(NB * LKE + 255) / 256, 256, 0, stream>>>(ctx, mu_c, rs_c, LKE, NB * LKE);
    stats_kernel<<<(NB * LQ + 255) / 256, 256, 0, stream>>>(qs_in, mu_q, rs_q, LQ, NB * LQ);
    ln_transpose_kernel<<<dim3(LKE / 64, DIMC / 64, NB), 256, 0, stream>>>(
        ctx, mu_c, rs_c, g_ctx, b_ctx, LKE, ctxT_hi, ctxT_lo);
    ln_transpose_kernel<<<dim3(LQ / 64, DIMC / 64, NB), 256, 0, stream>>>(
        qs_in, mu_q, rs_q, g_qs, b_qs, LQ, qsT_hi, qsT_lo);
    gemm_mfma_kernel<0><<<dim3(LKE / 128, 8, NB), 256, 0, stream>>>(
        w_kv, ctxT_hi, ctxT_lo, kf, vf);
    gemm_mfma_kernel<1><<<dim3(LQ / 128, 4, NB), 256, 0, stream>>>(
        w_q, qsT_hi, qsT_lo, qh, nullptr);
    qsample_kernel<<<dim3(TOPK / 64, NBH), 256, 0, stream>>>(
        qs_in, mu_q, rs_q, g_qs, b_qs, w_q, ridx, Qsm);
    cdist_min_kernel<<<dim3(LKE / 64, NBH), 256, 0, stream>>>(kf, Qsm, min_d);
    select_topk_kernel<<<NBH, 256, 0, stream>>>(min_d, isel);
    gather_k_kernel<<<(NBH * TOPK * 64) / 256, 256, 0, stream>>>(kf, isel, kselh);
    gather_vT_kernel<<<dim3(TOPK / 64, NBH), 256, 0, stream>>>(vf, isel, vTf);
    attn_mfma_kernel<<<dim3(LQ / 64, NBH), 256, 0, stream>>>(qh, kselh, vTf, afT_hi, afT_lo);
    gemm_mfma_kernel<2><<<dim3(LQ / 128, 2, NB), 256, 0, stream>>>(
        w_out, afT_hi, afT_lo, pre, nullptr);
    stats_loc_kernel<<<(NB * LQ) / 16, 256, 0, stream>>>(pre, mu_o, rs_o);
    final_kernel<<<dim3(LQ / 64, DIMC / 64, NB), 256, 0, stream>>>(
        pre, mu_o, rs_o, g_out, b_out, gamma, qs_in, out);
}

// Round 5
// 518.409 us; speedup vs baseline: 3.6796x; 1.0153x over previous
//
#include <hip/hip_runtime.h>
#include <hip/hip_bf16.h>
#include <math.h>

#define DIMC  256
#define HEADS 8
#define DH    64
#define INNER 512
#define TOPK  512
#define LQ    16384
#define LKE   4096
#define NB    2
#define NBH   16

typedef __attribute__((ext_vector_type(8))) short bf16x8;
typedef __attribute__((ext_vector_type(4))) float f32x4;

__device__ __forceinline__ unsigned short f2bf(float f) {
    unsigned u = __float_as_uint(f);
    u += 0x7FFFu + ((u >> 16) & 1u);
    return (unsigned short)(u >> 16);
}
__device__ __forceinline__ float bf2f(unsigned short b) {
    return __uint_as_float(((unsigned)b) << 16);
}
__device__ __forceinline__ f32x4 mfma16(bf16x8 a, bf16x8 b, f32x4 c) {
    return __builtin_amdgcn_mfma_f32_16x16x32_bf16(a, b, c, 0, 0, 0);
}
__device__ __forceinline__ unsigned f2q(float v) {   // monotone map [-1,1] -> u32
    return (unsigned)((int)rintf(v * 8388608.0f) + (1 << 24));
}

// ---------------- channel-LN stats: one thread per (b,l) ----------------
__global__ void stats_kernel(const float* __restrict__ x, float* __restrict__ mu,
                             float* __restrict__ rs, int L, int total) {
    int idx = blockIdx.x * 256 + threadIdx.x;
    if (idx >= total) return;
    int b = idx / L, l = idx - b * L;
    const float* p = x + (size_t)b * DIMC * L + l;
    float s = 0.f, sq = 0.f;
    for (int c = 0; c < DIMC; c++) {
        float v = p[(size_t)c * L];
        s += v; sq += v * v;
    }
    float m = s * (1.0f / DIMC);
    float var = fmaxf(sq * (1.0f / DIMC) - m * m, 0.f);
    mu[idx] = m;
    rs[idx] = rsqrtf(var + 1e-5f);
}

// ------- LN + transpose to [b][L][C], split into bf16 hi/lo planes -------
__global__ __launch_bounds__(256) void ln_transpose_kernel(
    const float* __restrict__ x, const float* __restrict__ mu, const float* __restrict__ rs,
    const float* __restrict__ g, const float* __restrict__ beta, int L,
    unsigned short* __restrict__ xhi, unsigned short* __restrict__ xlo) {
    int lt = blockIdx.x, ct = blockIdx.y, b = blockIdx.z;
    int l0 = lt * 64, c0 = ct * 64;
    int t = threadIdx.x;
    __shared__ float T[64][65];
#pragma unroll
    for (int r = 0; r < 16; r++) {
        int f = r * 256 + t;
        int l = f & 63, c = f >> 6;
        int loc = b * L + l0 + l;
        float v = x[((size_t)b * DIMC + c0 + c) * L + l0 + l];
        T[c][l] = (v - mu[loc]) * rs[loc] * g[c0 + c] + beta[c0 + c];
    }
    __syncthreads();
#pragma unroll
    for (int r = 0; r < 16; r++) {
        int f = r * 256 + t;
        int c = f & 63, l = f >> 6;
        float v = T[c][l];
        unsigned short hi = f2bf(v);
        size_t di = ((size_t)b * L + l0 + l) * DIMC + c0 + c;
        xhi[di] = hi;
        xlo[di] = f2bf(v - bf2f(hi));
    }
}

// ------------- split-bf16 MFMA GEMM, 128x128 tile, fused epilogues -------------
// MODE 0: KV proj  (M=1024,K=256,N=LKE)  rows<512 -> kf+kint (L2norm), rows>=512 -> vf
// MODE 1: Q  proj  (M=512, K=256,N=LQ)   all rows L2norm -> qh bf16
// MODE 2: OUT      (M=256, K=512,N=LQ)   -> pre [b][l][256] f32
template<int MODE>
__global__ __launch_bounds__(256) void gemm_mfma_kernel(
    const float* __restrict__ wmat,
    const unsigned short* __restrict__ xhi, const unsigned short* __restrict__ xlo,
    void* __restrict__ dst0, void* __restrict__ dst1, void* __restrict__ dst2) {
    constexpr int K = (MODE == 2) ? 512 : 256;
    constexpr int N = (MODE == 0) ? LKE : LQ;
    int n0 = blockIdx.x * 128;
    int by = blockIdx.y;
    int bb = blockIdx.z;
    int t = threadIdx.x, w = t >> 6, lane = t & 63;
    int wm = w >> 1, wn = w & 1;
    int lanelo = lane & 15, lanehi = lane >> 4;

    __shared__ __align__(16) char Wh[16384];
    __shared__ __align__(16) char Wl[16384];
    __shared__ __align__(16) char Xh[16384];
    __shared__ __align__(16) char Xl[16384];

    const float* wsrc = wmat + (size_t)by * 128 * K;
    const unsigned short* xsh = xhi + ((size_t)bb * N + n0) * K;
    const unsigned short* xsl = xlo + ((size_t)bb * N + n0) * K;

    f32x4 acc[4][4];
#pragma unroll
    for (int mi = 0; mi < 4; mi++)
#pragma unroll
        for (int ni = 0; ni < 4; ni++) acc[mi][ni] = (f32x4){0.f, 0.f, 0.f, 0.f};

    for (int k0 = 0; k0 < K; k0 += 64) {
        if (k0) __syncthreads();
#pragma unroll
        for (int gg = 0; gg < 4; gg++) {
            int e = gg * 2048 + t * 8;
            int row = e >> 6, kc = e & 63;
            const float* wp = wsrc + (size_t)row * K + k0 + kc;
            bf16x8 hi, lo;
#pragma unroll
            for (int i = 0; i < 8; i++) {
                float v = wp[i];
                unsigned short h = f2bf(v);
                hi[i] = (short)h;
                lo[i] = (short)f2bf(v - bf2f(h));
            }
            int off = (row * 128 + kc * 2) ^ ((row & 7) << 4);
            *(bf16x8*)(Wh + off) = hi;
            *(bf16x8*)(Wl + off) = lo;
            *(bf16x8*)(Xh + off) = *(const bf16x8*)(xsh + (size_t)row * K + k0 + kc);
            *(bf16x8*)(Xl + off) = *(const bf16x8*)(xsl + (size_t)row * K + k0 + kc);
        }
        __syncthreads();
#pragma unroll
        for (int kk = 0; kk < 2; kk++) {
            bf16x8 ah[4], al[4], bh_[4], bl_[4];
#pragma unroll
            for (int mi = 0; mi < 4; mi++) {
                int row = wm * 64 + mi * 16 + lanelo;
                int off = (row * 128 + kk * 64 + lanehi * 16) ^ ((row & 7) << 4);
                ah[mi] = *(const bf16x8*)(Wh + off);
                al[mi] = *(const bf16x8*)(Wl + off);
            }
#pragma unroll
            for (int ni = 0; ni < 4; ni++) {
                int row = wn * 64 + ni * 16 + lanelo;
                int off = (row * 128 + kk * 64 + lanehi * 16) ^ ((row & 7) << 4);
                bh_[ni] = *(const bf16x8*)(Xh + off);
                bl_[ni] = *(const bf16x8*)(Xl + off);
            }
#pragma unroll
            for (int mi = 0; mi < 4; mi++)
#pragma unroll
                for (int ni = 0; ni < 4; ni++) {
                    acc[mi][ni] = mfma16(ah[mi], bh_[ni], acc[mi][ni]);
                    acc[mi][ni] = mfma16(ah[mi], bl_[ni], acc[mi][ni]);
                    acc[mi][ni] = mfma16(al[mi], bh_[ni], acc[mi][ni]);
                }
        }
    }

    // epilogue
    bool donorm = (MODE == 1) || (MODE == 0 && by < 4);
    float inv[4];
    if (donorm) {
#pragma unroll
        for (int ni = 0; ni < 4; ni++) {
            float s = 0.f;
#pragma unroll
            for (int mi = 0; mi < 4; mi++)
#pragma unroll
                for (int rg = 0; rg < 4; rg++) s += acc[mi][ni][rg] * acc[mi][ni][rg];
            s += __shfl_xor(s, 16);
            s += __shfl_xor(s, 32);
            inv[ni] = 1.0f / fmaxf(sqrtf(s), 1e-12f);
        }
    }
#pragma unroll
    for (int mi = 0; mi < 4; mi++) {
        int rowg = by * 128 + wm * 64 + mi * 16 + lanehi * 4;
#pragma unroll
        for (int ni = 0; ni < 4; ni++) {
            int l = n0 + wn * 64 + ni * 16 + lanelo;
            if (MODE == 0) {
                bool isk = rowg < 512;
                float sc = isk ? inv[ni] : 1.0f;
                int h = (rowg >> 6) & 7, d0 = rowg & 63;
                float4 v = make_float4(acc[mi][ni][0] * sc, acc[mi][ni][1] * sc,
                                       acc[mi][ni][2] * sc, acc[mi][ni][3] * sc);
                float* dp = isk ? (float*)dst0 : (float*)dst1;
                size_t base = ((size_t)(bb * HEADS + h) * LKE + l) * 64 + d0;
                *(float4*)&dp[base] = v;
                if (isk) {
                    uint4 ui;
                    ui.x = f2q(v.x); ui.y = f2q(v.y); ui.z = f2q(v.z); ui.w = f2q(v.w);
                    *(uint4*)&((unsigned*)dst2)[base] = ui;
                }
            } else if (MODE == 1) {
                int h = rowg >> 6, d0 = rowg & 63;
                ushort4 u;
                u.x = f2bf(acc[mi][ni][0] * inv[ni]);
                u.y = f2bf(acc[mi][ni][1] * inv[ni]);
                u.z = f2bf(acc[mi][ni][2] * inv[ni]);
                u.w = f2bf(acc[mi][ni][3] * inv[ni]);
                unsigned short* qp = (unsigned short*)dst0;
                *(ushort4*)&qp[((size_t)(bb * HEADS + h) * LQ + l) * 64 + d0] = u;
            } else {
                float4 v = make_float4(acc[mi][ni][0], acc[mi][ni][1],
                                       acc[mi][ni][2], acc[mi][ni][3]);
                float* pp = (float*)dst0;
                *(float4*)&pp[((size_t)bb * LQ + l) * 256 + rowg] = v;
            }
        }
    }
}

// ------- exact f32 sampled-query recompute: LN -> w_q proj -> l2norm -> int ----
__global__ __launch_bounds__(256) void qsample_kernel(
    const float* __restrict__ x, const float* __restrict__ mu, const float* __restrict__ rs,
    const float* __restrict__ g, const float* __restrict__ beta,
    const float* __restrict__ w, const int* __restrict__ ridx,
    unsigned* __restrict__ Qint) {
    int lt = blockIdx.x, bh = blockIdx.y;
    int b = bh >> 3, h = bh & 7;
    int t = threadIdx.x, tx = t & 15, ty = t >> 4;
    __shared__ float Ws[64][33];
    __shared__ float Xs[32][65];
    __shared__ float Cs[64][65];
    __shared__ float nf[64];
    __shared__ int lidx[64];
    if (t < 64) lidx[t] = ridx[bh * TOPK + lt * 64 + t];
    __syncthreads();
    float acc[4][4];
#pragma unroll
    for (int a = 0; a < 4; a++)
#pragma unroll
        for (int c2 = 0; c2 < 4; c2++) acc[a][c2] = 0.f;
    for (int kc = 0; kc < DIMC; kc += 32) {
#pragma unroll
        for (int r = 0; r < 8; r++) {
            int f = r * 256 + t;
            int oi = f >> 5, kj = f & 31;
            Ws[oi][kj] = w[(size_t)(h * 64 + oi) * DIMC + kc + kj];
        }
#pragma unroll
        for (int r = 0; r < 8; r++) {
            int f = r * 256 + t;
            int kj = f >> 6, lj = f & 63;
            int l = lidx[lj];
            int loc = b * LQ + l;
            float v = x[(size_t)b * DIMC * LQ + (size_t)(kc + kj) * LQ + l];
            Xs[kj][lj] = (v - mu[loc]) * rs[loc] * g[kc + kj] + beta[kc + kj];
        }
        __syncthreads();
#pragma unroll
        for (int kj = 0; kj < 32; kj++) {
            float wr[4], xr[4];
#pragma unroll
            for (int a = 0; a < 4; a++) wr[a] = Ws[ty * 4 + a][kj];
#pragma unroll
            for (int c2 = 0; c2 < 4; c2++) xr[c2] = Xs[kj][tx * 4 + c2];
#pragma unroll
            for (int a = 0; a < 4; a++)
#pragma unroll
                for (int c2 = 0; c2 < 4; c2++) acc[a][c2] += wr[a] * xr[c2];
        }
        __syncthreads();
    }
#pragma unroll
    for (int a = 0; a < 4; a++)
#pragma unroll
        for (int c2 = 0; c2 < 4; c2++) Cs[ty * 4 + a][tx * 4 + c2] = acc[a][c2];
    __syncthreads();
    if (t < 64) {
        float sq = 0.f;
        for (int o = 0; o < 64; o++) { float v = Cs[o][t]; sq += v * v; }
        nf[t] = 1.0f / fmaxf(sqrtf(sq), 1e-12f);
    }
    __syncthreads();
#pragma unroll
    for (int r = 0; r < 16; r++) {
        int f = r * 256 + t;
        int d = f & 63, lj = f >> 6;
        Qint[((size_t)bh * TOPK + (size_t)lt * 64 + lj) * 64 + d] = f2q(Cs[d][lj] * nf[lj]);
    }
}

// -------- L1 cdist + min via integer v_sad_u32; K in VGPRs, Q via s_load --------
// grid (LKE/128, NBH, 2): blockDim 128, one key per lane, q range split in z.
__global__ __launch_bounds__(128) void cdist_sad_kernel(
    const unsigned* __restrict__ kint,  // [BH][LKE][64]
    const unsigned* __restrict__ Qint,  // [BH][TOPK][64]
    unsigned* __restrict__ min_d2) {    // [2][BH][LKE]
    int bh = blockIdx.y;
    int key = blockIdx.x * 128 + threadIdx.x;
    int qh = blockIdx.z;
    const unsigned* kp = kint + ((size_t)bh * LKE + key) * 64;
    unsigned k[64];
#pragma unroll
    for (int d4 = 0; d4 < 16; d4++) {
        uint4 v = *(const uint4*)(kp + d4 * 4);
        k[d4 * 4 + 0] = v.x; k[d4 * 4 + 1] = v.y;
        k[d4 * 4 + 2] = v.z; k[d4 * 4 + 3] = v.w;
    }
    const unsigned* qb = Qint + ((size_t)bh * TOPK + qh * (TOPK / 2)) * 64;
    unsigned best = 0xFFFFFFFFu;
    for (int qi = 0; qi < TOPK / 2; qi++) {
        const unsigned* q = qb + qi * 64;
        unsigned a0 = 0, a1 = 0, a2 = 0, a3 = 0;
#pragma unroll
        for (int d = 0; d < 64; d += 4) {
            unsigned q0 = q[d], q1 = q[d + 1], q2 = q[d + 2], q3 = q[d + 3];
            asm("v_sad_u32 %0, %1, %2, %0" : "+v"(a0) : "v"(k[d + 0]), "s"(q0));
            asm("v_sad_u32 %0, %1, %2, %0" : "+v"(a1) : "v"(k[d + 1]), "s"(q1));
            asm("v_sad_u32 %0, %1, %2, %0" : "+v"(a2) : "v"(k[d + 2]), "s"(q2));
            asm("v_sad_u32 %0, %1, %2, %0" : "+v"(a3) : "v"(k[d + 3]), "s"(q3));
        }
        unsigned s = (a0 + a1) + (a2 + a3);
        best = min(best, s);
    }
    min_d2[((size_t)qh * NBH + bh) * LKE + key] = best;
}

// ---------------- radix-select 512 smallest per row (deterministic) ----------
__global__ void select_topk_kernel(const unsigned* __restrict__ min_d2, int* __restrict__ isel) {
    int bh = blockIdx.x;
    int t = threadIdx.x;  // 256
    __shared__ unsigned su[LKE];
    __shared__ int hist[256];
    __shared__ int sb[2];
    for (int i = t; i < LKE; i += 256) {
        unsigned a = min_d2[(size_t)bh * LKE + i];
        unsigned b = min_d2[(size_t)(NBH + bh) * LKE + i];
        su[i] = min(a, b);
    }
    unsigned prefix = 0, mask = 0;
    int need = TOPK;
    for (int shift = 24; shift >= 0; shift -= 8) {
        hist[t] = 0;
        __syncthreads();
        for (int i = t; i < LKE; i += 256) {
            unsigned u = su[i];
            if ((u & mask) == prefix) atomicAdd(&hist[(u >> shift) & 255], 1);
        }
        __syncthreads();
        if (t == 0) {
            int c = 0, bsel = 0;
            for (; bsel < 255; bsel++) {
                if (c + hist[bsel] >= need) break;
                c += hist[bsel];
            }
            sb[0] = bsel; sb[1] = need - c;
        }
        __syncthreads();
        prefix |= ((unsigned)sb[0]) << shift;
        mask |= (255u << shift);
        need = sb[1];
        __syncthreads();
    }
    if (t < 64) {
        int pos = 0, eqseen = 0;
        unsigned long long lanem1 = (t == 0) ? 0ull : ((1ull << t) - 1ull);
        for (int i0 = 0; i0 < LKE; i0 += 64) {
            unsigned u = su[i0 + t];
            bool lt = (u < prefix);
            bool eq = (u == prefix);
            unsigned long long be = __ballot(eq);
            int eqbefore = __popcll(be & lanem1);
            bool take = lt || (eq && (eqseen + eqbefore) < need);
            unsigned long long bt = __ballot(take);
            if (take) isel[bh * TOPK + pos + __popcll(bt & lanem1)] = i0 + t;
            pos += __popcll(bt);
            eqseen += __popcll(be);
        }
    }
}

// ---------------- gather selected K (f32 -> bf16, [bh][key][d]) ----------------
__global__ void gather_k_kernel(const float* __restrict__ kf, const int* __restrict__ isel,
                                unsigned short* __restrict__ kselh) {
    int idx = blockIdx.x * 256 + threadIdx.x;
    int d = idx & 63;
    int ti = (idx >> 6) & (TOPK - 1);
    int bh = idx >> 15;
    int row = isel[bh * TOPK + ti];
    kselh[idx] = f2bf(kf[((size_t)bh * LKE + row) * 64 + d]);
}

// ---------------- gather selected V transposed (f32, [bh][d][key]) ------
__global__ __launch_bounds__(256) void gather_vT_kernel(
    const float* __restrict__ vf, const int* __restrict__ isel,
    float* __restrict__ vTf) {
    int bh = blockIdx.y, kc = blockIdx.x * 64;
    int t = threadIdx.x;
    __shared__ float T[64][65];
#pragma unroll
    for (int r = 0; r < 4; r++) {
        int c = r * 256 + t;          // 1024 float4 chunks
        int row = c >> 4, c4 = c & 15;
        int krow = isel[bh * TOPK + kc + row];
        float4 v = *(const float4*)(vf + ((size_t)bh * LKE + krow) * 64 + c4 * 4);
        T[row][c4 * 4 + 0] = v.x; T[row][c4 * 4 + 1] = v.y;
        T[row][c4 * 4 + 2] = v.z; T[row][c4 * 4 + 3] = v.w;
    }
    __syncthreads();
#pragma unroll
    for (int r = 0; r < 16; r++) {
        int f = r * 256 + t;
        int d = f >> 6, key = f & 63;
        vTf[(size_t)bh * 64 * TOPK + (size_t)d * TOPK + kc + key] = T[key][d];
    }
}

// ---------------- MFMA flash attention, split-precision PV ----------------
__global__ __launch_bounds__(256) void attn_mfma_kernel(
    const unsigned short* __restrict__ qh,    // [BH][LQ][64] bf16
    const unsigned short* __restrict__ kselh, // [BH][512][64] bf16
    const float* __restrict__ vTf,            // [BH][64][512] f32
    unsigned short* __restrict__ afT_hi,      // [b][LQ][512]
    unsigned short* __restrict__ afT_lo) {
    int bh = blockIdx.y, rt = blockIdx.x;
    int bq = bh >> 3, h = bh & 7;
    int t = threadIdx.x, w = t >> 6, lane = t & 63;
    __shared__ unsigned short Qs[64 * 64];
    __shared__ unsigned short Ks[64 * 64];
    __shared__ unsigned short Vhi[64 * 64];
    __shared__ unsigned short Vlo[64 * 64];
    __shared__ unsigned short Phi[4 * 16 * 64];
    __shared__ unsigned short Plo[4 * 16 * 64];

    const unsigned short* qb = qh + ((size_t)bh * LQ + (size_t)rt * 64) * 64;
    const unsigned short* kb = kselh + (size_t)bh * TOPK * 64;
    const float* vb = vTf + (size_t)bh * 64 * TOPK;

#pragma unroll
    for (int r = 0; r < 2; r++) {
        int c = r * 256 + t; int row = c >> 3, c8 = c & 7;
        bf16x8 v = *(const bf16x8*)(qb + row * 64 + c8 * 8);
        *(bf16x8*)((char*)Qs + ((row * 128 + c8 * 16) ^ ((row & 7) << 4))) = v;
    }
    auto stageKV = [&](int kc0) {
#pragma unroll
        for (int r = 0; r < 2; r++) {
            int c = r * 256 + t; int row = c >> 3, c8 = c & 7;
            int off = (row * 128 + c8 * 16) ^ ((row & 7) << 4);
            bf16x8 kv = *(const bf16x8*)(kb + (kc0 + row) * 64 + c8 * 8);
            *(bf16x8*)((char*)Ks + off) = kv;
            const float* vp = vb + (size_t)row * TOPK + kc0 + c8 * 8;
            bf16x8 hi, lo;
#pragma unroll
            for (int i = 0; i < 8; i++) {
                float v = vp[i];
                unsigned short hh = f2bf(v);
                hi[i] = (short)hh;
                lo[i] = (short)f2bf(v - bf2f(hh));
            }
            *(bf16x8*)((char*)Vhi + off) = hi;
            *(bf16x8*)((char*)Vlo + off) = lo;
        }
    };
    stageKV(0);
    __syncthreads();

    bf16x8 qfrag[2];
#pragma unroll
    for (int kk = 0; kk < 2; kk++) {
        int row = w * 16 + (lane & 15);
        qfrag[kk] = *(const bf16x8*)((char*)Qs +
            ((row * 128 + kk * 64 + (lane >> 4) * 16) ^ ((row & 7) << 4)));
    }

    f32x4 o[4];
#pragma unroll
    for (int m = 0; m < 4; m++) o[m] = (f32x4){0.f, 0.f, 0.f, 0.f};
    float lsum[4] = {0.f, 0.f, 0.f, 0.f};
    unsigned short* pwh = Phi + w * 16 * 64;
    unsigned short* pwl = Plo + w * 16 * 64;

    for (int ch = 0; ch < 8; ch++) {
        f32x4 s[4];
#pragma unroll
        for (int n = 0; n < 4; n++) {
            s[n] = (f32x4){0.f, 0.f, 0.f, 0.f};
#pragma unroll
            for (int kk = 0; kk < 2; kk++) {
                int row = n * 16 + (lane & 15);
                bf16x8 kfr = *(const bf16x8*)((char*)Ks +
                    ((row * 128 + kk * 64 + (lane >> 4) * 16) ^ ((row & 7) << 4)));
                s[n] = mfma16(qfrag[kk], kfr, s[n]);
            }
        }
        float part[4] = {0.f, 0.f, 0.f, 0.f};
#pragma unroll
        for (int n = 0; n < 4; n++) {
#pragma unroll
            for (int rg = 0; rg < 4; rg++) {
                float p = __expf(s[n][rg]);
                part[rg] += p;
                unsigned short ph = f2bf(p);
                unsigned short pl = f2bf(p - bf2f(ph));
                int row = (lane >> 4) * 4 + rg, col = n * 16 + (lane & 15);
                int off = (row * 128 + col * 2) ^ ((row & 7) << 4);
                *(unsigned short*)((char*)pwh + off) = ph;
                *(unsigned short*)((char*)pwl + off) = pl;
            }
        }
#pragma unroll
        for (int rg = 0; rg < 4; rg++) {
            float v = part[rg];
            v += __shfl_xor(v, 1); v += __shfl_xor(v, 2);
            v += __shfl_xor(v, 4); v += __shfl_xor(v, 8);
            lsum[rg] += v;
        }
        bf16x8 pfh[2], pfl[2];
#pragma unroll
        for (int kk = 0; kk < 2; kk++) {
            int row = lane & 15;
            int off = (row * 128 + kk * 64 + (lane >> 4) * 16) ^ ((row & 7) << 4);
            pfh[kk] = *(const bf16x8*)((char*)pwh + off);
            pfl[kk] = *(const bf16x8*)((char*)pwl + off);
        }
#pragma unroll
        for (int m = 0; m < 4; m++) {
#pragma unroll
            for (int kk = 0; kk < 2; kk++) {
                int row = m * 16 + (lane & 15);
                int off = (row * 128 + kk * 64 + (lane >> 4) * 16) ^ ((row & 7) << 4);
                bf16x8 vh = *(const bf16x8*)((char*)Vhi + off);
                bf16x8 vl = *(const bf16x8*)((char*)Vlo + off);
                o[m] = mfma16(pfh[kk], vh, o[m]);
                o[m] = mfma16(pfh[kk], vl, o[m]);
                o[m] = mfma16(pfl[kk], vh, o[m]);
            }
        }
        if (ch < 7) {
            __syncthreads();
            stageKV((ch + 1) * 64);
            __syncthreads();
        }
    }
    int row0 = w * 16 + (lane >> 4) * 4;
#pragma unroll
    for (int rg = 0; rg < 4; rg++) {
        float invs = 1.0f / lsum[rg];
        int l = rt * 64 + row0 + rg;
        size_t base = ((size_t)bq * LQ + l) * 512 + h * 64 + (lane & 15);
#pragma unroll
        for (int m = 0; m < 4; m++) {
            float v = o[m][rg] * invs;
            unsigned short hb = f2bf(v);
            afT_hi[base + m * 16] = hb;
            afT_lo[base + m * 16] = f2bf(v - bf2f(hb));
        }
    }
}

// ---------------- per-location stats over 256 channels (pre is [b][l][256]) ----
__global__ void stats_loc_kernel(const float* __restrict__ pre, float* __restrict__ mu,
                                 float* __restrict__ rs) {
    int t = threadIdx.x;
    int grp = t >> 4, ln = t & 15;
    int loc = blockIdx.x * 16 + grp;
    const float4* p = (const float4*)(pre + (size_t)loc * 256);
    float s = 0.f, sq = 0.f;
#pragma unroll
    for (int i = 0; i < 4; i++) {
        float4 v = p[ln + i * 16];
        s += v.x + v.y + v.z + v.w;
        sq += v.x * v.x + v.y * v.y + v.z * v.z + v.w * v.w;
    }
#pragma unroll
    for (int d = 1; d < 16; d <<= 1) {
        s += __shfl_xor(s, d);
        sq += __shfl_xor(sq, d);
    }
    if (ln == 0) {
        float m = s * (1.0f / 256.0f);
        float var = fmaxf(sq * (1.0f / 256.0f) - m * m, 0.f);
        mu[loc] = m;
        rs[loc] = rsqrtf(var + 1e-5f);
    }
}

// ---------------- final LN + gamma*x + residual (transpose to [b][ch][l]) ------
__global__ __launch_bounds__(256) void final_kernel(
    const float* __restrict__ pre, const float* __restrict__ mu,
    const float* __restrict__ rs, const float* __restrict__ g,
    const float* __restrict__ beta, const float* __restrict__ gamma,
    const float* __restrict__ qs_in, float* __restrict__ out) {
    int lt = blockIdx.x, ot = blockIdx.y, b = blockIdx.z;
    int l0 = lt * 64, o0 = ot * 64;
    int t = threadIdx.x;
    __shared__ float T[64][65];
    float gm = gamma[0];
#pragma unroll
    for (int r = 0; r < 16; r++) {
        int f = r * 256 + t;
        int o = f & 63, l = f >> 6;
        int loc = b * LQ + l0 + l;
        float v = pre[(size_t)loc * 256 + o0 + o];
        T[o][l] = ((v - mu[loc]) * rs[loc] * g[o0 + o] + beta[o0 + o]) * gm;
    }
    __syncthreads();
#pragma unroll
    for (int r = 0; r < 16; r++) {
        int f = r * 256 + t;
        int l = f & 63, o = f >> 6;
        size_t oi = ((size_t)(b * DIMC + o0 + o)) * LQ + l0 + l;
        out[oi] = T[o][l] + qs_in[oi];
    }
}

extern "C" void kernel_launch(void* const* d_in, const int* in_sizes, int n_in,
                              void* d_out, int out_size, void* d_ws, size_t ws_size,
                              hipStream_t stream) {
    const float* qs_in = (const float*)d_in[0];
    const float* ctx   = (const float*)d_in[1];
    const int*   ridx  = (const int*)d_in[2];
    const float* g_ctx = (const float*)d_in[3];
    const float* b_ctx = (const float*)d_in[4];
    const float* g_qs  = (const float*)d_in[5];
    const float* b_qs  = (const float*)d_in[6];
    const float* w_kv  = (const float*)d_in[7];
    const float* w_q   = (const float*)d_in[8];
    const float* w_out = (const float*)d_in[9];
    const float* g_out = (const float*)d_in[10];
    const float* b_out = (const float*)d_in[11];
    const float* gamma = (const float*)d_in[12];
    float* out = (float*)d_out;

    char* ws = (char*)d_ws;
    size_t off = 0;
    auto alloc = [&](size_t bytes) { char* p = ws + off; off += (bytes + 255) & ~(size_t)255; return p; };

    float*          kf    = (float*)alloc((size_t)NBH * LKE * 64 * 4);
    float*          vf    = (float*)alloc((size_t)NBH * LKE * 64 * 4);
    unsigned*       kint  = (unsigned*)alloc((size_t)NBH * LKE * 64 * 4);
    unsigned short* qh    = (unsigned short*)alloc((size_t)NBH * LQ * 64 * 2);
    // union region: {ctxT_hi, ctxT_lo, qsT_hi, qsT_lo} (early) / {afT_hi, afT_lo} (late)
    char*           uni   = alloc((size_t)2 * NB * LQ * INNER * 2);
    unsigned short* ctxT_hi = (unsigned short*)(uni);
    unsigned short* ctxT_lo = (unsigned short*)(uni + (size_t)NB * LKE * DIMC * 2);
    unsigned short* qsT_hi  = (unsigned short*)(uni + (size_t)2 * NB * LKE * DIMC * 2);
    unsigned short* qsT_lo  = (unsigned short*)(uni + (size_t)2 * NB * LKE * DIMC * 2 + (size_t)NB * LQ * DIMC * 2);
    unsigned short* afT_hi  = (unsigned short*)(uni);
    unsigned short* afT_lo  = (unsigned short*)(uni + (size_t)NB * LQ * INNER * 2);

    unsigned*       Qint  = (unsigned*)alloc((size_t)NBH * TOPK * 64 * 4);
    unsigned short* kselh = (unsigned short*)alloc((size_t)NBH * TOPK * 64 * 2);
    float*          vTf   = (float*)alloc((size_t)NBH * 64 * TOPK * 4);
    float*          pre   = (float*)alloc((size_t)NB * LQ * DIMC * 4);
    unsigned*       min_d2= (unsigned*)alloc((size_t)2 * NBH * LKE * 4);
    float*          mu_c  = (float*)alloc(NB * LKE * 4);
    float*          rs_c  = (float*)alloc(NB * LKE * 4);
    float*          mu_q  = (float*)alloc(NB * LQ * 4);
    float*          rs_q  = (float*)alloc(NB * LQ * 4);
    float*          mu_o  = (float*)alloc(NB * LQ * 4);
    float*          rs_o  = (float*)alloc(NB * LQ * 4);
    int*            isel  = (int*)alloc(NBH * TOPK * 4);

    stats_kernel<<<(NB * LKE + 255) / 256, 256, 0, stream>>>(ctx, mu_c, rs_c, LKE, NB * LKE);
    stats_kernel<<<(NB * LQ + 255) / 256, 256, 0, stream>>>(qs_in, mu_q, rs_q, LQ, NB * LQ);
    ln_transpose_kernel<<<dim3(LKE / 64, DIMC / 64, NB), 256, 0, stream>>>(
        ctx, mu_c, rs_c, g_ctx, b_ctx, LKE, ctxT_hi, ctxT_lo);
    ln_transpose_kernel<<<dim3(LQ / 64, DIMC / 64, NB), 256, 0, stream>>>(
        qs_in, mu_q, rs_q, g_qs, b_qs, LQ, qsT_hi, qsT_lo);
    gemm_mfma_kernel<0><<<dim3(LKE / 128, 8, NB), 256, 0, stream>>>(
        w_kv, ctxT_hi, ctxT_lo, kf, vf, kint);
    gemm_mfma_kernel<1><<<dim3(LQ / 128, 4, NB), 256, 0, stream>>>(
        w_q, qsT_hi, qsT_lo, qh, nullptr, nullptr);
    qsample_kernel<<<dim3(TOPK / 64, NBH), 256, 0, stream>>>(
        qs_in, mu_q, rs_q, g_qs, b_qs, w_q, ridx, Qint);
    cdist_sad_kernel<<<dim3(LKE / 128, NBH, 2), 128, 0, stream>>>(kint, Qint, min_d2);
    select_topk_kernel<<<NBH, 256, 0, stream>>>(min_d2, isel);
    gather_k_kernel<<<(NBH * TOPK * 64) / 256, 256, 0, stream>>>(kf, isel, kselh);
    gather_vT_kernel<<<dim3(TOPK / 64, NBH), 256, 0, stream>>>(vf, isel, vTf);
    attn_mfma_kernel<<<dim3(LQ / 64, NBH), 256, 0, stream>>>(qh, kselh, vTf, afT_hi, afT_lo);
    gemm_mfma_kernel<2><<<dim3(LQ / 128, 2, NB), 256, 0, stream>>>(
        w_out, afT_hi, afT_lo, pre, nullptr, nullptr);
    stats_loc_kernel<<<(NB * LQ) / 16, 256, 0, stream>>>(pre, mu_o, rs_o);
    final_kernel<<<dim3(LQ / 64, DIMC / 64, NB), 256, 0, stream>>>(
        pre, mu_o, rs_o, g_out, b_out, gamma, qs_in, out);
}

// Round 6
// 409.090 us; speedup vs baseline: 4.6629x; 1.2672x over previous
//
#include <hip/hip_runtime.h>
#include <hip/hip_bf16.h>
#include <math.h>

#define DIMC  256
#define HEADS 8
#define DH    64
#define INNER 512
#define TOPK  512
#define LQ    16384
#define LKE   4096
#define NB    2
#define NBH   16

typedef __attribute__((ext_vector_type(8))) short bf16x8;
typedef __attribute__((ext_vector_type(4))) float f32x4;

__device__ __forceinline__ unsigned short f2bf(float f) {
    unsigned u = __float_as_uint(f);
    u += 0x7FFFu + ((u >> 16) & 1u);
    return (unsigned short)(u >> 16);
}
__device__ __forceinline__ float bf2f(unsigned short b) {
    return __uint_as_float(((unsigned)b) << 16);
}
__device__ __forceinline__ f32x4 mfma16(bf16x8 a, bf16x8 b, f32x4 c) {
    return __builtin_amdgcn_mfma_f32_16x16x32_bf16(a, b, c, 0, 0, 0);
}
__device__ __forceinline__ unsigned f2q(float v) {   // monotone map [-1,1] -> u32
    return (unsigned)((int)rintf(v * 8388608.0f) + (1 << 24));
}

// ---------------- channel-LN stats: one thread per (b,l) ----------------
__global__ void stats_kernel(const float* __restrict__ x, float* __restrict__ mu,
                             float* __restrict__ rs, int L, int total) {
    int idx = blockIdx.x * 256 + threadIdx.x;
    if (idx >= total) return;
    int b = idx / L, l = idx - b * L;
    const float* p = x + (size_t)b * DIMC * L + l;
    float s = 0.f, sq = 0.f;
    for (int c = 0; c < DIMC; c++) {
        float v = p[(size_t)c * L];
        s += v; sq += v * v;
    }
    float m = s * (1.0f / DIMC);
    float var = fmaxf(sq * (1.0f / DIMC) - m * m, 0.f);
    mu[idx] = m;
    rs[idx] = rsqrtf(var + 1e-5f);
}

// ------- LN + transpose to [b][L][C], bf16 hi (and optional lo) planes -------
template<bool WRITELO>
__global__ __launch_bounds__(256) void ln_transpose_kernel(
    const float* __restrict__ x, const float* __restrict__ mu, const float* __restrict__ rs,
    const float* __restrict__ g, const float* __restrict__ beta, int L,
    unsigned short* __restrict__ xhi, unsigned short* __restrict__ xlo) {
    int lt = blockIdx.x, ct = blockIdx.y, b = blockIdx.z;
    int l0 = lt * 64, c0 = ct * 64;
    int t = threadIdx.x;
    __shared__ float T[64][65];
#pragma unroll
    for (int r = 0; r < 16; r++) {
        int f = r * 256 + t;
        int l = f & 63, c = f >> 6;
        int loc = b * L + l0 + l;
        float v = x[((size_t)b * DIMC + c0 + c) * L + l0 + l];
        T[c][l] = (v - mu[loc]) * rs[loc] * g[c0 + c] + beta[c0 + c];
    }
    __syncthreads();
#pragma unroll
    for (int r = 0; r < 16; r++) {
        int f = r * 256 + t;
        int c = f & 63, l = f >> 6;
        float v = T[c][l];
        unsigned short hi = f2bf(v);
        size_t di = ((size_t)b * L + l0 + l) * DIMC + c0 + c;
        xhi[di] = hi;
        if (WRITELO) xlo[di] = f2bf(v - bf2f(hi));
    }
}

// ------------- MFMA GEMM, 128x128 tile, fused epilogues -------------
// MODE 0: KV proj  (M=1024,K=256,N=LKE)  rows<512 -> kf+kint (L2norm, SPLIT-precision),
//                                        rows>=512 -> vf (single bf16)
// MODE 1: Q  proj  (M=512, K=256,N=LQ)   single bf16, L2norm -> qh bf16
// MODE 2: OUT      (M=256, K=512,N=LQ)   single bf16 -> pre [b][l][256] f32
template<int MODE>
__global__ __launch_bounds__(256) void gemm_mfma_kernel(
    const float* __restrict__ wmat,
    const unsigned short* __restrict__ xhi, const unsigned short* __restrict__ xlo,
    void* __restrict__ dst0, void* __restrict__ dst1, void* __restrict__ dst2) {
    constexpr int K = (MODE == 2) ? 512 : 256;
    constexpr int N = (MODE == 0) ? LKE : LQ;
    constexpr bool MAYSPLIT = (MODE == 0);
    int n0 = blockIdx.x * 128;
    int by = blockIdx.y;
    int bb = blockIdx.z;
    int t = threadIdx.x, w = t >> 6, lane = t & 63;
    int wm = w >> 1, wn = w & 1;
    int lanelo = lane & 15, lanehi = lane >> 4;

    __shared__ __align__(16) char Wh[16384];
    __shared__ __align__(16) char Xh[16384];
    __shared__ __align__(16) char Wl[MAYSPLIT ? 16384 : 16];
    __shared__ __align__(16) char Xl[MAYSPLIT ? 16384 : 16];

    bool split = MAYSPLIT && (by < 4);   // only the K-projection rows need split precision

    const float* wsrc = wmat + (size_t)by * 128 * K;
    const unsigned short* xsh = xhi + ((size_t)bb * N + n0) * K;
    const unsigned short* xsl = xlo + ((size_t)bb * N + n0) * K;

    f32x4 acc[4][4];
#pragma unroll
    for (int mi = 0; mi < 4; mi++)
#pragma unroll
        for (int ni = 0; ni < 4; ni++) acc[mi][ni] = (f32x4){0.f, 0.f, 0.f, 0.f};

    for (int k0 = 0; k0 < K; k0 += 64) {
        if (k0) __syncthreads();
#pragma unroll
        for (int gg = 0; gg < 4; gg++) {
            int e = gg * 2048 + t * 8;
            int row = e >> 6, kc = e & 63;
            const float* wp = wsrc + (size_t)row * K + k0 + kc;
            bf16x8 hi, lo;
#pragma unroll
            for (int i = 0; i < 8; i++) {
                float v = wp[i];
                unsigned short h = f2bf(v);
                hi[i] = (short)h;
                if (MAYSPLIT) lo[i] = (short)f2bf(v - bf2f(h));
            }
            int off = (row * 128 + kc * 2) ^ ((row & 7) << 4);
            *(bf16x8*)(Wh + off) = hi;
            *(bf16x8*)(Xh + off) = *(const bf16x8*)(xsh + (size_t)row * K + k0 + kc);
            if (split) {
                *(bf16x8*)(Wl + off) = lo;
                *(bf16x8*)(Xl + off) = *(const bf16x8*)(xsl + (size_t)row * K + k0 + kc);
            }
        }
        __syncthreads();
#pragma unroll
        for (int kk = 0; kk < 2; kk++) {
            bf16x8 ah[4], bh_[4];
#pragma unroll
            for (int mi = 0; mi < 4; mi++) {
                int row = wm * 64 + mi * 16 + lanelo;
                int off = (row * 128 + kk * 64 + lanehi * 16) ^ ((row & 7) << 4);
                ah[mi] = *(const bf16x8*)(Wh + off);
            }
#pragma unroll
            for (int ni = 0; ni < 4; ni++) {
                int row = wn * 64 + ni * 16 + lanelo;
                int off = (row * 128 + kk * 64 + lanehi * 16) ^ ((row & 7) << 4);
                bh_[ni] = *(const bf16x8*)(Xh + off);
            }
#pragma unroll
            for (int mi = 0; mi < 4; mi++)
#pragma unroll
                for (int ni = 0; ni < 4; ni++)
                    acc[mi][ni] = mfma16(ah[mi], bh_[ni], acc[mi][ni]);
            if (split) {
                bf16x8 al[4], bl_[4];
#pragma unroll
                for (int mi = 0; mi < 4; mi++) {
                    int row = wm * 64 + mi * 16 + lanelo;
                    int off = (row * 128 + kk * 64 + lanehi * 16) ^ ((row & 7) << 4);
                    al[mi] = *(const bf16x8*)(Wl + off);
                }
#pragma unroll
                for (int ni = 0; ni < 4; ni++) {
                    int row = wn * 64 + ni * 16 + lanelo;
                    int off = (row * 128 + kk * 64 + lanehi * 16) ^ ((row & 7) << 4);
                    bl_[ni] = *(const bf16x8*)(Xl + off);
                }
#pragma unroll
                for (int mi = 0; mi < 4; mi++)
#pragma unroll
                    for (int ni = 0; ni < 4; ni++) {
                        acc[mi][ni] = mfma16(ah[mi], bl_[ni], acc[mi][ni]);
                        acc[mi][ni] = mfma16(al[mi], bh_[ni], acc[mi][ni]);
                    }
            }
        }
    }

    // epilogue
    bool donorm = (MODE == 1) || (MODE == 0 && by < 4);
    float inv[4];
    if (donorm) {
#pragma unroll
        for (int ni = 0; ni < 4; ni++) {
            float s = 0.f;
#pragma unroll
            for (int mi = 0; mi < 4; mi++)
#pragma unroll
                for (int rg = 0; rg < 4; rg++) s += acc[mi][ni][rg] * acc[mi][ni][rg];
            s += __shfl_xor(s, 16);
            s += __shfl_xor(s, 32);
            inv[ni] = 1.0f / fmaxf(sqrtf(s), 1e-12f);
        }
    }
#pragma unroll
    for (int mi = 0; mi < 4; mi++) {
        int rowg = by * 128 + wm * 64 + mi * 16 + lanehi * 4;
#pragma unroll
        for (int ni = 0; ni < 4; ni++) {
            int l = n0 + wn * 64 + ni * 16 + lanelo;
            if (MODE == 0) {
                bool isk = rowg < 512;
                float sc = isk ? inv[ni] : 1.0f;
                int h = (rowg >> 6) & 7, d0 = rowg & 63;
                float4 v = make_float4(acc[mi][ni][0] * sc, acc[mi][ni][1] * sc,
                                       acc[mi][ni][2] * sc, acc[mi][ni][3] * sc);
                float* dp = isk ? (float*)dst0 : (float*)dst1;
                size_t base = ((size_t)(bb * HEADS + h) * LKE + l) * 64 + d0;
                *(float4*)&dp[base] = v;
                if (isk) {
                    uint4 ui;
                    ui.x = f2q(v.x); ui.y = f2q(v.y); ui.z = f2q(v.z); ui.w = f2q(v.w);
                    *(uint4*)&((unsigned*)dst2)[base] = ui;
                }
            } else if (MODE == 1) {
                int h = rowg >> 6, d0 = rowg & 63;
                ushort4 u;
                u.x = f2bf(acc[mi][ni][0] * inv[ni]);
                u.y = f2bf(acc[mi][ni][1] * inv[ni]);
                u.z = f2bf(acc[mi][ni][2] * inv[ni]);
                u.w = f2bf(acc[mi][ni][3] * inv[ni]);
                unsigned short* qp = (unsigned short*)dst0;
                *(ushort4*)&qp[((size_t)(bb * HEADS + h) * LQ + l) * 64 + d0] = u;
            } else {
                float4 v = make_float4(acc[mi][ni][0], acc[mi][ni][1],
                                       acc[mi][ni][2], acc[mi][ni][3]);
                float* pp = (float*)dst0;
                *(float4*)&pp[((size_t)bb * LQ + l) * 256 + rowg] = v;
            }
        }
    }
}

// ------- exact f32 sampled-query recompute: LN -> w_q proj -> l2norm -> int ----
__global__ __launch_bounds__(256) void qsample_kernel(
    const float* __restrict__ x, const float* __restrict__ mu, const float* __restrict__ rs,
    const float* __restrict__ g, const float* __restrict__ beta,
    const float* __restrict__ w, const int* __restrict__ ridx,
    unsigned* __restrict__ Qint) {
    int lt = blockIdx.x, bh = blockIdx.y;
    int b = bh >> 3, h = bh & 7;
    int t = threadIdx.x, tx = t & 15, ty = t >> 4;
    __shared__ float Ws[64][33];
    __shared__ float Xs[32][65];
    __shared__ float Cs[64][65];
    __shared__ float nf[64];
    __shared__ int lidx[64];
    if (t < 64) lidx[t] = ridx[bh * TOPK + lt * 64 + t];
    __syncthreads();
    float acc[4][4];
#pragma unroll
    for (int a = 0; a < 4; a++)
#pragma unroll
        for (int c2 = 0; c2 < 4; c2++) acc[a][c2] = 0.f;
    for (int kc = 0; kc < DIMC; kc += 32) {
#pragma unroll
        for (int r = 0; r < 8; r++) {
            int f = r * 256 + t;
            int oi = f >> 5, kj = f & 31;
            Ws[oi][kj] = w[(size_t)(h * 64 + oi) * DIMC + kc + kj];
        }
#pragma unroll
        for (int r = 0; r < 8; r++) {
            int f = r * 256 + t;
            int kj = f >> 6, lj = f & 63;
            int l = lidx[lj];
            int loc = b * LQ + l;
            float v = x[(size_t)b * DIMC * LQ + (size_t)(kc + kj) * LQ + l];
            Xs[kj][lj] = (v - mu[loc]) * rs[loc] * g[kc + kj] + beta[kc + kj];
        }
        __syncthreads();
#pragma unroll
        for (int kj = 0; kj < 32; kj++) {
            float wr[4], xr[4];
#pragma unroll
            for (int a = 0; a < 4; a++) wr[a] = Ws[ty * 4 + a][kj];
#pragma unroll
            for (int c2 = 0; c2 < 4; c2++) xr[c2] = Xs[kj][tx * 4 + c2];
#pragma unroll
            for (int a = 0; a < 4; a++)
#pragma unroll
                for (int c2 = 0; c2 < 4; c2++) acc[a][c2] += wr[a] * xr[c2];
        }
        __syncthreads();
    }
#pragma unroll
    for (int a = 0; a < 4; a++)
#pragma unroll
        for (int c2 = 0; c2 < 4; c2++) Cs[ty * 4 + a][tx * 4 + c2] = acc[a][c2];
    __syncthreads();
    if (t < 64) {
        float sq = 0.f;
        for (int o = 0; o < 64; o++) { float v = Cs[o][t]; sq += v * v; }
        nf[t] = 1.0f / fmaxf(sqrtf(sq), 1e-12f);
    }
    __syncthreads();
#pragma unroll
    for (int r = 0; r < 16; r++) {
        int f = r * 256 + t;
        int d = f & 63, lj = f >> 6;
        Qint[((size_t)bh * TOPK + (size_t)lt * 64 + lj) * 64 + d] = f2q(Cs[d][lj] * nf[lj]);
    }
}

// -------- L1 cdist + min via integer v_sad_u32; K in VGPRs, Q via s_load --------
// grid (LKE/128, NBH, 4): blockDim 128, one key per lane, q range split in z.
__global__ __launch_bounds__(128) void cdist_sad_kernel(
    const unsigned* __restrict__ kint,  // [BH][LKE][64]
    const unsigned* __restrict__ Qint,  // [BH][TOPK][64]
    unsigned* __restrict__ min_d4) {    // [4][BH][LKE]
    int bh = blockIdx.y;
    int key = blockIdx.x * 128 + threadIdx.x;
    int qz = blockIdx.z;
    const unsigned* kp = kint + ((size_t)bh * LKE + key) * 64;
    unsigned k[64];
#pragma unroll
    for (int d4 = 0; d4 < 16; d4++) {
        uint4 v = *(const uint4*)(kp + d4 * 4);
        k[d4 * 4 + 0] = v.x; k[d4 * 4 + 1] = v.y;
        k[d4 * 4 + 2] = v.z; k[d4 * 4 + 3] = v.w;
    }
    const unsigned* qb = Qint + ((size_t)bh * TOPK + qz * (TOPK / 4)) * 64;
    unsigned best = 0xFFFFFFFFu;
    for (int qi = 0; qi < TOPK / 4; qi++) {
        const unsigned* q = qb + qi * 64;
        unsigned a0 = 0, a1 = 0, a2 = 0, a3 = 0;
#pragma unroll
        for (int d = 0; d < 64; d += 4) {
            unsigned q0 = q[d], q1 = q[d + 1], q2 = q[d + 2], q3 = q[d + 3];
            asm("v_sad_u32 %0, %1, %2, %0" : "+v"(a0) : "v"(k[d + 0]), "s"(q0));
            asm("v_sad_u32 %0, %1, %2, %0" : "+v"(a1) : "v"(k[d + 1]), "s"(q1));
            asm("v_sad_u32 %0, %1, %2, %0" : "+v"(a2) : "v"(k[d + 2]), "s"(q2));
            asm("v_sad_u32 %0, %1, %2, %0" : "+v"(a3) : "v"(k[d + 3]), "s"(q3));
        }
        unsigned s = (a0 + a1) + (a2 + a3);
        best = min(best, s);
    }
    min_d4[((size_t)qz * NBH + bh) * LKE + key] = best;
}

// ---------------- radix-select 512 smallest per row (deterministic) ----------
__global__ void select_topk_kernel(const unsigned* __restrict__ min_d4, int* __restrict__ isel) {
    int bh = blockIdx.x;
    int t = threadIdx.x;  // 256
    __shared__ unsigned su[LKE];
    __shared__ int hist[256];
    __shared__ int sb[2];
    for (int i = t; i < LKE; i += 256) {
        unsigned a = min(min_d4[(size_t)bh * LKE + i],
                         min_d4[(size_t)(NBH + bh) * LKE + i]);
        unsigned b = min(min_d4[(size_t)(2 * NBH + bh) * LKE + i],
                         min_d4[(size_t)(3 * NBH + bh) * LKE + i]);
        su[i] = min(a, b);
    }
    unsigned prefix = 0, mask = 0;
    int need = TOPK;
    for (int shift = 24; shift >= 0; shift -= 8) {
        hist[t] = 0;
        __syncthreads();
        for (int i = t; i < LKE; i += 256) {
            unsigned u = su[i];
            if ((u & mask) == prefix) atomicAdd(&hist[(u >> shift) & 255], 1);
        }
        __syncthreads();
        if (t == 0) {
            int c = 0, bsel = 0;
            for (; bsel < 255; bsel++) {
                if (c + hist[bsel] >= need) break;
                c += hist[bsel];
            }
            sb[0] = bsel; sb[1] = need - c;
        }
        __syncthreads();
        prefix |= ((unsigned)sb[0]) << shift;
        mask |= (255u << shift);
        need = sb[1];
        __syncthreads();
    }
    if (t < 64) {
        int pos = 0, eqseen = 0;
        unsigned long long lanem1 = (t == 0) ? 0ull : ((1ull << t) - 1ull);
        for (int i0 = 0; i0 < LKE; i0 += 64) {
            unsigned u = su[i0 + t];
            bool lt = (u < prefix);
            bool eq = (u == prefix);
            unsigned long long be = __ballot(eq);
            int eqbefore = __popcll(be & lanem1);
            bool take = lt || (eq && (eqseen + eqbefore) < need);
            unsigned long long bt = __ballot(take);
            if (take) isel[bh * TOPK + pos + __popcll(bt & lanem1)] = i0 + t;
            pos += __popcll(bt);
            eqseen += __popcll(be);
        }
    }
}

// ---------------- gather selected K (f32 -> bf16, [bh][key][d]) ----------------
__global__ void gather_k_kernel(const float* __restrict__ kf, const int* __restrict__ isel,
                                unsigned short* __restrict__ kselh) {
    int idx = blockIdx.x * 256 + threadIdx.x;
    int d = idx & 63;
    int ti = (idx >> 6) & (TOPK - 1);
    int bh = idx >> 15;
    int row = isel[bh * TOPK + ti];
    kselh[idx] = f2bf(kf[((size_t)bh * LKE + row) * 64 + d]);
}

// ---------------- gather selected V transposed (f32 -> bf16, [bh][d][key]) ------
__global__ __launch_bounds__(256) void gather_vT_kernel(
    const float* __restrict__ vf, const int* __restrict__ isel,
    unsigned short* __restrict__ vTh) {
    int bh = blockIdx.y, kc = blockIdx.x * 64;
    int t = threadIdx.x;
    __shared__ float T[64][65];
#pragma unroll
    for (int r = 0; r < 4; r++) {
        int c = r * 256 + t;          // 1024 float4 chunks
        int row = c >> 4, c4 = c & 15;
        int krow = isel[bh * TOPK + kc + row];
        float4 v = *(const float4*)(vf + ((size_t)bh * LKE + krow) * 64 + c4 * 4);
        T[row][c4 * 4 + 0] = v.x; T[row][c4 * 4 + 1] = v.y;
        T[row][c4 * 4 + 2] = v.z; T[row][c4 * 4 + 3] = v.w;
    }
    __syncthreads();
#pragma unroll
    for (int r = 0; r < 16; r++) {
        int f = r * 256 + t;
        int d = f >> 6, key = f & 63;
        vTh[(size_t)bh * 64 * TOPK + (size_t)d * TOPK + kc + key] = f2bf(T[key][d]);
    }
}

// ---------------- MFMA flash attention (single-bf16 P,V; f32 accum) ------------
// scores bounded in [-1,1] (q,k L2-normalized) -> no max subtraction needed.
__global__ __launch_bounds__(256) void attn_mfma_kernel(
    const unsigned short* __restrict__ qh,    // [BH][LQ][64] bf16
    const unsigned short* __restrict__ kselh, // [BH][512][64] bf16
    const unsigned short* __restrict__ vTh,   // [BH][64][512] bf16
    unsigned short* __restrict__ afT) {       // [b][LQ][512] bf16
    int bh = blockIdx.y, rt = blockIdx.x;
    int bq = bh >> 3, h = bh & 7;
    int t = threadIdx.x, w = t >> 6, lane = t & 63;
    __shared__ unsigned short Qs[64 * 64];
    __shared__ unsigned short Ks[64 * 64];
    __shared__ unsigned short Vts[64 * 64];
    __shared__ unsigned short Ps[4 * 16 * 64];

    const unsigned short* qb = qh + ((size_t)bh * LQ + (size_t)rt * 64) * 64;
    const unsigned short* kb = kselh + (size_t)bh * TOPK * 64;
    const unsigned short* vb = vTh + (size_t)bh * 64 * TOPK;

#pragma unroll
    for (int r = 0; r < 2; r++) {
        int c = r * 256 + t; int row = c >> 3, c8 = c & 7;
        bf16x8 v = *(const bf16x8*)(qb + row * 64 + c8 * 8);
        *(bf16x8*)((char*)Qs + ((row * 128 + c8 * 16) ^ ((row & 7) << 4))) = v;
    }
    auto stageKV = [&](int kc0) {
#pragma unroll
        for (int r = 0; r < 2; r++) {
            int c = r * 256 + t; int row = c >> 3, c8 = c & 7;
            int off = (row * 128 + c8 * 16) ^ ((row & 7) << 4);
            *(bf16x8*)((char*)Ks + off) = *(const bf16x8*)(kb + (kc0 + row) * 64 + c8 * 8);
            *(bf16x8*)((char*)Vts + off) = *(const bf16x8*)(vb + row * TOPK + kc0 + c8 * 8);
        }
    };
    stageKV(0);
    __syncthreads();

    bf16x8 qfrag[2];
#pragma unroll
    for (int kk = 0; kk < 2; kk++) {
        int row = w * 16 + (lane & 15);
        qfrag[kk] = *(const bf16x8*)((char*)Qs +
            ((row * 128 + kk * 64 + (lane >> 4) * 16) ^ ((row & 7) << 4)));
    }

    f32x4 o[4];
#pragma unroll
    for (int m = 0; m < 4; m++) o[m] = (f32x4){0.f, 0.f, 0.f, 0.f};
    float lsum[4] = {0.f, 0.f, 0.f, 0.f};
    unsigned short* pw = Ps + w * 16 * 64;

    for (int ch = 0; ch < 8; ch++) {
        f32x4 s[4];
#pragma unroll
        for (int n = 0; n < 4; n++) {
            s[n] = (f32x4){0.f, 0.f, 0.f, 0.f};
#pragma unroll
            for (int kk = 0; kk < 2; kk++) {
                int row = n * 16 + (lane & 15);
                bf16x8 kfr = *(const bf16x8*)((char*)Ks +
                    ((row * 128 + kk * 64 + (lane >> 4) * 16) ^ ((row & 7) << 4)));
                s[n] = mfma16(qfrag[kk], kfr, s[n]);
            }
        }
        float part[4] = {0.f, 0.f, 0.f, 0.f};
#pragma unroll
        for (int n = 0; n < 4; n++) {
#pragma unroll
            for (int rg = 0; rg < 4; rg++) {
                float p = __expf(s[n][rg]);
                part[rg] += p;
                int row = (lane >> 4) * 4 + rg, col = n * 16 + (lane & 15);
                *(unsigned short*)((char*)pw +
                    ((row * 128 + col * 2) ^ ((row & 7) << 4))) = f2bf(p);
            }
        }
#pragma unroll
        for (int rg = 0; rg < 4; rg++) {
            float v = part[rg];
            v += __shfl_xor(v, 1); v += __shfl_xor(v, 2);
            v += __shfl_xor(v, 4); v += __shfl_xor(v, 8);
            lsum[rg] += v;
        }
        bf16x8 pfrag[2];
#pragma unroll
        for (int kk = 0; kk < 2; kk++) {
            int row = lane & 15;
            pfrag[kk] = *(const bf16x8*)((char*)pw +
                ((row * 128 + kk * 64 + (lane >> 4) * 16) ^ ((row & 7) << 4)));
        }
#pragma unroll
        for (int m = 0; m < 4; m++) {
#pragma unroll
            for (int kk = 0; kk < 2; kk++) {
                int row = m * 16 + (lane & 15);
                bf16x8 vfr = *(const bf16x8*)((char*)Vts +
                    ((row * 128 + kk * 64 + (lane >> 4) * 16) ^ ((row & 7) << 4)));
                o[m] = mfma16(pfrag[kk], vfr, o[m]);
            }
        }
        if (ch < 7) {
            __syncthreads();
            stageKV((ch + 1) * 64);
            __syncthreads();
        }
    }
    int row0 = w * 16 + (lane >> 4) * 4;
#pragma unroll
    for (int rg = 0; rg < 4; rg++) {
        float invs = 1.0f / lsum[rg];
        int l = rt * 64 + row0 + rg;
        size_t base = ((size_t)bq * LQ + l) * 512 + h * 64 + (lane & 15);
#pragma unroll
        for (int m = 0; m < 4; m++)
            afT[base + m * 16] = f2bf(o[m][rg] * invs);
    }
}

// ---------------- per-location stats over 256 channels (pre is [b][l][256]) ----
__global__ void stats_loc_kernel(const float* __restrict__ pre, float* __restrict__ mu,
                                 float* __restrict__ rs) {
    int t = threadIdx.x;
    int grp = t >> 4, ln = t & 15;
    int loc = blockIdx.x * 16 + grp;
    const float4* p = (const float4*)(pre + (size_t)loc * 256);
    float s = 0.f, sq = 0.f;
#pragma unroll
    for (int i = 0; i < 4; i++) {
        float4 v = p[ln + i * 16];
        s += v.x + v.y + v.z + v.w;
        sq += v.x * v.x + v.y * v.y + v.z * v.z + v.w * v.w;
    }
#pragma unroll
    for (int d = 1; d < 16; d <<= 1) {
        s += __shfl_xor(s, d);
        sq += __shfl_xor(sq, d);
    }
    if (ln == 0) {
        float m = s * (1.0f / 256.0f);
        float var = fmaxf(sq * (1.0f / 256.0f) - m * m, 0.f);
        mu[loc] = m;
        rs[loc] = rsqrtf(var + 1e-5f);
    }
}

// ---------------- final LN + gamma*x + residual (transpose to [b][ch][l]) ------
__global__ __launch_bounds__(256) void final_kernel(
    const float* __restrict__ pre, const float* __restrict__ mu,
    const float* __restrict__ rs, const float* __restrict__ g,
    const float* __restrict__ beta, const float* __restrict__ gamma,
    const float* __restrict__ qs_in, float* __restrict__ out) {
    int lt = blockIdx.x, ot = blockIdx.y, b = blockIdx.z;
    int l0 = lt * 64, o0 = ot * 64;
    int t = threadIdx.x;
    __shared__ float T[64][65];
    float gm = gamma[0];
#pragma unroll
    for (int r = 0; r < 16; r++) {
        int f = r * 256 + t;
        int o = f & 63, l = f >> 6;
        int loc = b * LQ + l0 + l;
        float v = pre[(size_t)loc * 256 + o0 + o];
        T[o][l] = ((v - mu[loc]) * rs[loc] * g[o0 + o] + beta[o0 + o]) * gm;
    }
    __syncthreads();
#pragma unroll
    for (int r = 0; r < 16; r++) {
        int f = r * 256 + t;
        int l = f & 63, o = f >> 6;
        size_t oi = ((size_t)(b * DIMC + o0 + o)) * LQ + l0 + l;
        out[oi] = T[o][l] + qs_in[oi];
    }
}

extern "C" void kernel_launch(void* const* d_in, const int* in_sizes, int n_in,
                              void* d_out, int out_size, void* d_ws, size_t ws_size,
                              hipStream_t stream) {
    const float* qs_in = (const float*)d_in[0];
    const float* ctx   = (const float*)d_in[1];
    const int*   ridx  = (const int*)d_in[2];
    const float* g_ctx = (const float*)d_in[3];
    const float* b_ctx = (const float*)d_in[4];
    const float* g_qs  = (const float*)d_in[5];
    const float* b_qs  = (const float*)d_in[6];
    const float* w_kv  = (const float*)d_in[7];
    const float* w_q   = (const float*)d_in[8];
    const float* w_out = (const float*)d_in[9];
    const float* g_out = (const float*)d_in[10];
    const float* b_out = (const float*)d_in[11];
    const float* gamma = (const float*)d_in[12];
    float* out = (float*)d_out;

    char* ws = (char*)d_ws;
    size_t off = 0;
    auto alloc = [&](size_t bytes) { char* p = ws + off; off += (bytes + 255) & ~(size_t)255; return p; };

    float*          kf    = (float*)alloc((size_t)NBH * LKE * 64 * 4);
    float*          vf    = (float*)alloc((size_t)NBH * LKE * 64 * 4);
    unsigned*       kint  = (unsigned*)alloc((size_t)NBH * LKE * 64 * 4);
    unsigned short* qh    = (unsigned short*)alloc((size_t)NBH * LQ * 64 * 2);
    // union region: {ctxT_hi, ctxT_lo, qsT_hi} (early) / {afT} (late, after gemm<1>)
    char*           uni   = alloc((size_t)NB * LQ * INNER * 2);   // 33.6 MB
    unsigned short* ctxT_hi = (unsigned short*)(uni);
    unsigned short* ctxT_lo = (unsigned short*)(uni + (size_t)NB * LKE * DIMC * 2);
    unsigned short* qsT_hi  = (unsigned short*)(uni + (size_t)2 * NB * LKE * DIMC * 2);
    unsigned short* afT     = (unsigned short*)(uni);

    unsigned*       Qint  = (unsigned*)alloc((size_t)NBH * TOPK * 64 * 4);
    unsigned short* kselh = (unsigned short*)alloc((size_t)NBH * TOPK * 64 * 2);
    unsigned short* vTh   = (unsigned short*)alloc((size_t)NBH * 64 * TOPK * 2);
    float*          pre   = (float*)alloc((size_t)NB * LQ * DIMC * 4);
    unsigned*       min_d4= (unsigned*)alloc((size_t)4 * NBH * LKE * 4);
    float*          mu_c  = (float*)alloc(NB * LKE * 4);
    float*          rs_c  = (float*)alloc(NB * LKE * 4);
    float*          mu_q  = (float*)alloc(NB * LQ * 4);
    float*          rs_q  = (float*)alloc(NB * LQ * 4);
    float*          mu_o  = (float*)alloc(NB * LQ * 4);
    float*          rs_o  = (float*)alloc(NB * LQ * 4);
    int*            isel  = (int*)alloc(NBH * TOPK * 4);

    stats_kernel<<<(NB * LKE + 255) / 256, 256, 0, stream>>>(ctx, mu_c, rs_c, LKE, NB * LKE);
    stats_kernel<<<(NB * LQ + 255) / 256, 256, 0, stream>>>(qs_in, mu_q, rs_q, LQ, NB * LQ);
    ln_transpose_kernel<true><<<dim3(LKE / 64, DIMC / 64, NB), 256, 0, stream>>>(
        ctx, mu_c, rs_c, g_ctx, b_ctx, LKE, ctxT_hi, ctxT_lo);
    ln_transpose_kernel<false><<<dim3(LQ / 64, DIMC / 64, NB), 256, 0, stream>>>(
        qs_in, mu_q, rs_q, g_qs, b_qs, LQ, qsT_hi, nullptr);
    gemm_mfma_kernel<0><<<dim3(LKE / 128, 8, NB), 256, 0, stream>>>(
        w_kv, ctxT_hi, ctxT_lo, kf, vf, kint);
    gemm_mfma_kernel<1><<<dim3(LQ / 128, 4, NB), 256, 0, stream>>>(
        w_q, qsT_hi, qsT_hi, qh, nullptr, nullptr);
    qsample_kernel<<<dim3(TOPK / 64, NBH), 256, 0, stream>>>(
        qs_in, mu_q, rs_q, g_qs, b_qs, w_q, ridx, Qint);
    cdist_sad_kernel<<<dim3(LKE / 128, NBH, 4), 128, 0, stream>>>(kint, Qint, min_d4);
    select_topk_kernel<<<NBH, 256, 0, stream>>>(min_d4, isel);
    gather_k_kernel<<<(NBH * TOPK * 64) / 256, 256, 0, stream>>>(kf, isel, kselh);
    gather_vT_kernel<<<dim3(TOPK / 64, NBH), 256, 0, stream>>>(vf, isel, vTh);
    attn_mfma_kernel<<<dim3(LQ / 64, NBH), 256, 0, stream>>>(qh, kselh, vTh, afT);
    gemm_mfma_kernel<2><<<dim3(LQ / 128, 2, NB), 256, 0, stream>>>(
        w_out, afT, afT, pre, nullptr, nullptr);
    stats_loc_kernel<<<(NB * LQ) / 16, 256, 0, stream>>>(pre, mu_o, rs_o);
    final_kernel<<<dim3(LQ / 64, DIMC / 64, NB), 256, 0, stream>>>(
        pre, mu_o, rs_o, g_out, b_out, gamma, qs_in, out);
}